// Round 2
// baseline (3979.662 us; speedup 1.0000x reference)
//
#include <hip/hip_runtime.h>
#include <math.h>

#define BB 16
#define CC 256
#define HH 64
#define WW 64
#define HWs 4096
#define PP 65536   // BB*HWs
#define QQ 8
#define NN 9

__device__ __forceinline__ float gelu_f(float x) {
    return 0.5f * x * (1.0f + erff(x * 0.70710678118654752f));
}

// ---------------- tiny weight-transpose prep ----------------
// wt[tap][k][ci]  <- off_w[k][ci][tap]   (27,256,3,3) -> (9,27,256)
// dwt[tap][c]     <- dw_w[c][0][tap]     (256,1,3,3)  -> (9,256)
__global__ void prep_weights_kernel(const float* __restrict__ off0_w, const float* __restrict__ off1_w,
                                    const float* __restrict__ dw0_w, const float* __restrict__ dw1_w,
                                    const float* __restrict__ op1_w,
                                    float* __restrict__ wt0, float* __restrict__ wt1,
                                    float* __restrict__ dwt0, float* __restrict__ dwt1,
                                    float* __restrict__ op1t) {
    int i = blockIdx.x * 256 + threadIdx.x;
    if (i < 9*27*256) {
        int ci = i & 255;
        int k = (i >> 8) % 27;
        int tap = i / (27*256);
        wt0[i] = off0_w[(k*256 + ci)*9 + tap];
        wt1[i] = off1_w[(k*256 + ci)*9 + tap];
    }
    if (i < 9*256) {
        int c = i & 255;
        int tap = i >> 8;
        dwt0[i] = dw0_w[c*9 + tap];
        dwt1[i] = dw1_w[c*9 + tap];
        op1t[i] = op1_w[c*9 + tap];
    }
}

// ---------------- token path ----------------
__global__ void token_kernel(const float* __restrict__ inter, const float* __restrict__ intra,
                             const float* __restrict__ proj_w, const float* __restrict__ proj_b,
                             const float* __restrict__ lin_w, const float* __restrict__ lin_b,
                             const float* __restrict__ tok_g, const float* __restrict__ tok_b,
                             float* __restrict__ t_out) {
    int bq = blockIdx.x;
    int b = bq >> 3, q = bq & 7;
    int c = threadIdx.x;
    __shared__ float inter_s[256];
    __shared__ float pt_s[9];
    __shared__ float g_s[256];
    __shared__ float red[256];
    __shared__ float stat[2];
    inter_s[c] = inter[(b*QQ + q)*CC + c];
    __syncthreads();
    for (int n = 0; n < 9; n++) {
        red[c] = inter_s[c] * intra[(b*NN + n)*CC + c];
        __syncthreads();
        for (int s = 128; s > 0; s >>= 1) {
            if (c < s) red[c] += red[c + s];
            __syncthreads();
        }
        if (c == 0) pt_s[n] = red[0];
        __syncthreads();
    }
    float u = proj_b[c];
    for (int k = 0; k < 256; k++) u += inter_s[k] * proj_w[k*CC + c];
    for (int n = 0; n < 9; n++) u += pt_s[n] * proj_w[(256 + n)*CC + c];
    g_s[c] = gelu_f(u);
    __syncthreads();
    float v = lin_b[c];
    for (int k = 0; k < 256; k++) v += g_s[k] * lin_w[k*CC + c];
    red[c] = v;
    __syncthreads();
    for (int s = 128; s > 0; s >>= 1) { if (c < s) red[c] += red[c + s]; __syncthreads(); }
    if (c == 0) stat[0] = red[0] * (1.0f/256.0f);
    __syncthreads();
    float m = stat[0];
    red[c] = (v - m)*(v - m);
    __syncthreads();
    for (int s = 128; s > 0; s >>= 1) { if (c < s) red[c] += red[c + s]; __syncthreads(); }
    if (c == 0) stat[1] = red[0] * (1.0f/256.0f);
    __syncthreads();
    float var = stat[1];
    float r = rsqrtf(var + 1e-5f);
    t_out[(b*QQ + q)*CC + c] = (v - m) * r * tok_g[c] + tok_b[c];
}

// ---------------- img = ie*(1+pe), NCHW -> NHWC transpose ----------------
// grid (HWs/32, CC/32, BB) block (32,8)
__global__ void img_pe_kernel(const float* __restrict__ ie, const float* __restrict__ intra,
                              const float* __restrict__ masks, float* __restrict__ img) {
    int b = blockIdx.z;
    int c0 = blockIdx.y * 32;
    int s0 = blockIdx.x * 32;
    __shared__ float tile[32][33];
    __shared__ float intra_s[9][32];
    __shared__ float mask_s[9][32];
    int tx = threadIdx.x, ty = threadIdx.y;
    int t = ty*32 + tx;
    for (int i = t; i < 288; i += 256) {
        int n = i >> 5, j = i & 31;
        intra_s[n][j] = intra[(b*NN + n)*CC + c0 + j];
        mask_s[n][j]  = masks[(b*NN + n)*HWs + s0 + j];
    }
    __syncthreads();
    #pragma unroll
    for (int r = 0; r < 4; r++) {
        int cl = ty + 8*r;
        float val = ie[(b*CC + c0 + cl)*HWs + s0 + tx];
        float pe = 0.f;
        #pragma unroll
        for (int n = 0; n < 9; n++) pe += intra_s[n][cl] * mask_s[n][tx];
        tile[cl][tx] = val * (1.0f + pe);
    }
    __syncthreads();
    #pragma unroll
    for (int r = 0; r < 4; r++) {
        int sl = ty + 8*r;
        img[(b*HWs + s0 + sl)*CC + c0 + tx] = tile[tx][sl];
    }
}

// ---------------- generic NHWC 1x1 conv (GEMM) ----------------
// out[p,co] = (RES? res[p,co]:0) + maybe_gelu(bias[co] + sum_ci in[p,ci]*W[co,ci])
template<int CI, int CO, int ACT, bool RES>
__global__ void __launch_bounds__(256) conv1x1_kernel(const float* __restrict__ in, const float* __restrict__ Wt,
        const float* __restrict__ bias, const float* __restrict__ res, float* __restrict__ out) {
    constexpr int CI4 = CI/4;
    constexpr int CO4 = CO/4;
    constexpr int NCOG = CO/4;       // co-groups of 4
    constexpr int PG = 256 / NCOG;   // p-groups
    constexpr int PPT = 64 / PG;     // rows per thread
    __shared__ float4 in_s[64*CI4];
    int t = threadIdx.x;
    int p0 = blockIdx.x * 64;
    const float4* inf = (const float4*)in;
    for (int i = t; i < 64*CI4; i += 256) in_s[i] = inf[p0*CI4 + i];
    __syncthreads();
    int cog = t % NCOG;
    int pg = t / NCOG;
    int co = cog * 4;
    float acc[4][PPT];
    #pragma unroll
    for (int j = 0; j < 4; j++)
        #pragma unroll
        for (int pp = 0; pp < PPT; pp++) acc[j][pp] = 0.f;
    const float4* Wf = (const float4*)Wt;
    for (int k = 0; k < CI4; k++) {
        float4 w0 = Wf[(co+0)*CI4 + k];
        float4 w1 = Wf[(co+1)*CI4 + k];
        float4 w2 = Wf[(co+2)*CI4 + k];
        float4 w3 = Wf[(co+3)*CI4 + k];
        #pragma unroll
        for (int pp = 0; pp < PPT; pp++) {
            float4 xv = in_s[(pg*PPT + pp)*CI4 + k];
            acc[0][pp] += xv.x*w0.x + xv.y*w0.y + xv.z*w0.z + xv.w*w0.w;
            acc[1][pp] += xv.x*w1.x + xv.y*w1.y + xv.z*w1.z + xv.w*w1.w;
            acc[2][pp] += xv.x*w2.x + xv.y*w2.y + xv.z*w2.z + xv.w*w2.w;
            acc[3][pp] += xv.x*w3.x + xv.y*w3.y + xv.z*w3.z + xv.w*w3.w;
        }
    }
    float b0 = bias[co], b1 = bias[co+1], b2 = bias[co+2], b3 = bias[co+3];
    #pragma unroll
    for (int pp = 0; pp < PPT; pp++) {
        int p = p0 + pg*PPT + pp;
        float4 v;
        v.x = acc[0][pp] + b0; v.y = acc[1][pp] + b1; v.z = acc[2][pp] + b2; v.w = acc[3][pp] + b3;
        if (ACT == 1) { v.x = gelu_f(v.x); v.y = gelu_f(v.y); v.z = gelu_f(v.z); v.w = gelu_f(v.w); }
        if (RES) {
            float4 rv = ((const float4*)res)[p*CO4 + cog];
            v.x += rv.x; v.y += rv.y; v.z += rv.z; v.w += rv.w;
        }
        ((float4*)out)[p*CO4 + cog] = v;
    }
}

// ---------------- 3x3 offset conv (27 out channels), NHWC in, [p][27] out ----------------
// one block per (b,h) image row; wt is pre-transposed [tap][k][ci]
template<int DIL>
__global__ void __launch_bounds__(256) off_conv_kernel(const float* __restrict__ x, const float* __restrict__ wt,
        const float* __restrict__ bias, float* __restrict__ off) {
    __shared__ float4 xs[4096];  // xor-swizzled: value (w,c4) at xs[c4*64 + (w^c4)]
    int bh = blockIdx.x;
    int b = bh >> 6, h = bh & 63;
    int t = threadIdx.x;
    int w = t & 63;
    int kq = t >> 6;
    float acc[7];
    #pragma unroll
    for (int j = 0; j < 7; j++) acc[j] = 0.f;
    const float4* wtf = (const float4*)wt;
    for (int ki = 0; ki < 3; ki++) {
        int hrow = h + (ki - 1)*DIL;
        __syncthreads();
        if (hrow >= 0 && hrow < 64) {
            const float4* row = (const float4*)(x + ((size_t)(b*64 + hrow)*64) * 256);
            for (int i = t; i < 4096; i += 256) {
                int ww = i >> 6, c4 = i & 63;
                xs[c4*64 + (ww ^ c4)] = row[ww*64 + c4];
            }
        } else {
            float4 z = make_float4(0.f,0.f,0.f,0.f);
            for (int i = t; i < 4096; i += 256) xs[i] = z;
        }
        __syncthreads();
        for (int kj = 0; kj < 3; kj++) {
            int wcol = w + (kj - 1)*DIL;
            if (wcol < 0 || wcol >= 64) continue;
            for (int k4 = 0; k4 < 64; k4++) {
                float4 xv = xs[k4*64 + (wcol ^ k4)];
                #pragma unroll
                for (int j = 0; j < 7; j++) {
                    int k = kq*7 + j;
                    if (k < 27) {
                        float4 wv = wtf[((ki*3 + kj)*27 + k)*64 + k4];
                        acc[j] += xv.x*wv.x + xv.y*wv.y + xv.z*wv.z + xv.w*wv.w;
                    }
                }
            }
        }
    }
    int p = (b*64 + h)*64 + w;
    #pragma unroll
    for (int j = 0; j < 7; j++) {
        int k = kq*7 + j;
        if (k < 27) off[p*27 + k] = acc[j] + bias[k];
    }
}

// ---------------- modulated deformable depthwise 3x3 ----------------
// block per (b,h); wave handles 16 positions; lane = c4 (4 channels)
template<int DIL>
__global__ void __launch_bounds__(256) deform_kernel(const float* __restrict__ src, const float* __restrict__ off,
        const float* __restrict__ dwt, const float* __restrict__ dwb, float* __restrict__ out) {
    int bh = blockIdx.x;
    int b = bh >> 6, h = bh & 63;
    int t = threadIdx.x;
    int c4 = t & 63;
    int ps = t >> 6;
    float4 dwv[9];
    #pragma unroll
    for (int kk = 0; kk < 9; kk++) dwv[kk] = ((const float4*)dwt)[kk*64 + c4];
    float4 bv = ((const float4*)dwb)[c4];
    const float4* srcf = (const float4*)src;
    for (int i = 0; i < 16; i++) {
        int w = ps*16 + i;
        int p = (b*64 + h)*64 + w;
        const float* op = off + (size_t)p*27;
        float4 acc = make_float4(0.f,0.f,0.f,0.f);
        #pragma unroll
        for (int kk = 0; kk < 9; kk++) {
            int ki = kk / 3, kj = kk % 3;
            float ox = op[kk];
            float oy = op[9 + kk];
            float mm = op[18 + kk];
            mm = 1.0f / (1.0f + expf(-mm));
            float py = (float)(h - DIL + ki*DIL) + oy;
            float px = (float)(w - DIL + kj*DIL) + ox;
            float y0f = floorf(py), x0f = floorf(px);
            float wy = py - y0f, wx = px - x0f;
            int y0 = (int)y0f, x0 = (int)x0f;
            int y1 = y0 + 1, x1 = x0 + 1;
            float w00 = (1.f - wy)*(1.f - wx), w01 = (1.f - wy)*wx;
            float w10 = wy*(1.f - wx), w11 = wy*wx;
            float4 s = make_float4(0.f,0.f,0.f,0.f);
            bool xv0 = (x0 >= 0) && (x0 < 64);
            bool xv1 = (x1 >= 0) && (x1 < 64);
            if (y0 >= 0 && y0 < 64) {
                const float4* r0 = srcf + (size_t)((b*64 + y0)*64) * 64;
                if (xv0) { float4 v = r0[x0*64 + c4]; s.x += v.x*w00; s.y += v.y*w00; s.z += v.z*w00; s.w += v.w*w00; }
                if (xv1) { float4 v = r0[x1*64 + c4]; s.x += v.x*w01; s.y += v.y*w01; s.z += v.z*w01; s.w += v.w*w01; }
            }
            if (y1 >= 0 && y1 < 64) {
                const float4* r1 = srcf + (size_t)((b*64 + y1)*64) * 64;
                if (xv0) { float4 v = r1[x0*64 + c4]; s.x += v.x*w10; s.y += v.y*w10; s.z += v.z*w10; s.w += v.w*w10; }
                if (xv1) { float4 v = r1[x1*64 + c4]; s.x += v.x*w11; s.y += v.y*w11; s.z += v.z*w11; s.w += v.w*w11; }
            }
            acc.x += s.x * mm * dwv[kk].x;
            acc.y += s.y * mm * dwv[kk].y;
            acc.z += s.z * mm * dwv[kk].z;
            acc.w += s.w * mm * dwv[kk].w;
        }
        float4 o4;
        o4.x = acc.x + bv.x; o4.y = acc.y + bv.y; o4.z = acc.z + bv.z; o4.w = acc.w + bv.w;
        ((float4*)out)[(size_t)p*64 + c4] = o4;
    }
}

// ---------------- xg = x*a + img; LayerNorm over C ----------------
__global__ void __launch_bounds__(256) gate_ln_kernel(const float* __restrict__ x, const float* __restrict__ a,
        const float* __restrict__ img, const float* __restrict__ g, const float* __restrict__ bb,
        float* __restrict__ out) {
    int t = threadIdx.x;
    int lane = t & 63;
    int wv = t >> 6;
    int p = blockIdx.x*4 + wv;
    float4 xv = ((const float4*)x)[p*64 + lane];
    float4 av = ((const float4*)a)[p*64 + lane];
    float4 iv = ((const float4*)img)[p*64 + lane];
    float4 v;
    v.x = xv.x*av.x + iv.x; v.y = xv.y*av.y + iv.y;
    v.z = xv.z*av.z + iv.z; v.w = xv.w*av.w + iv.w;
    float s = v.x + v.y + v.z + v.w;
    float s2 = v.x*v.x + v.y*v.y + v.z*v.z + v.w*v.w;
    #pragma unroll
    for (int o = 1; o < 64; o <<= 1) { s += __shfl_xor(s, o); s2 += __shfl_xor(s2, o); }
    float m = s * (1.f/256.f);
    float var = s2 * (1.f/256.f) - m*m;
    float r = rsqrtf(var + 1e-5f);
    float4 gv = ((const float4*)g)[lane];
    float4 bv = ((const float4*)bb)[lane];
    float4 o4;
    o4.x = (v.x - m)*r*gv.x + bv.x;
    o4.y = (v.y - m)*r*gv.y + bv.y;
    o4.z = (v.z - m)*r*gv.z + bv.z;
    o4.w = (v.w - m)*r*gv.w + bv.w;
    ((float4*)out)[p*64 + lane] = o4;
}

// ---------------- depthwise 3x3 pad=1 + gelu (NHWC) ----------------
__global__ void __launch_bounds__(256) dw3x3_kernel(const float* __restrict__ in, const float* __restrict__ wt,
        const float* __restrict__ bias, float* __restrict__ out) {
    int gid = blockIdx.x*256 + threadIdx.x;
    int c4 = gid & 63;
    int p = gid >> 6;
    int w = p & 63;
    int h = (p >> 6) & 63;
    int b = p >> 12;
    float4 acc = ((const float4*)bias)[c4];
    #pragma unroll
    for (int ki = 0; ki < 3; ki++) {
        int hh = h + ki - 1;
        if (hh < 0 || hh >= 64) continue;
        #pragma unroll
        for (int kj = 0; kj < 3; kj++) {
            int wwp = w + kj - 1;
            if (wwp < 0 || wwp >= 64) continue;
            float4 v = ((const float4*)in)[((b*64 + hh)*64 + wwp)*64 + c4];
            float4 wv = ((const float4*)wt)[(ki*3 + kj)*64 + c4];
            acc.x += v.x*wv.x; acc.y += v.y*wv.y; acc.z += v.z*wv.z; acc.w += v.w*wv.w;
        }
    }
    acc.x = gelu_f(acc.x); acc.y = gelu_f(acc.y); acc.z = gelu_f(acc.z); acc.w = gelu_f(acc.w);
    ((float4*)out)[p*64 + c4] = acc;
}

// ---------------- 8-token cross attention + alpha residual ----------------
__global__ void __launch_bounds__(256) attn_kernel(const float* __restrict__ dense, const float* __restrict__ tok,
        const float* __restrict__ alpha, float* __restrict__ out) {
    __shared__ float4 t_s[8*64];
    __shared__ float4 al_s[64];
    int bh = blockIdx.x;
    int b = bh >> 6, h = bh & 63;
    int t = threadIdx.x;
    for (int i = t; i < 512; i += 256) t_s[i] = ((const float4*)tok)[b*512 + i];
    if (t < 64) al_s[t] = ((const float4*)alpha)[t];
    __syncthreads();
    int lane = t & 63, ps = t >> 6;
    for (int i = 0; i < 16; i++) {
        int w = ps*16 + i;
        int p = (b*64 + h)*64 + w;
        float4 dv = ((const float4*)dense)[p*64 + lane];
        float sc[8];
        #pragma unroll
        for (int q = 0; q < 8; q++) {
            float4 tv = t_s[q*64 + lane];
            float partial = dv.x*tv.x + dv.y*tv.y + dv.z*tv.z + dv.w*tv.w;
            #pragma unroll
            for (int o = 1; o < 64; o <<= 1) partial += __shfl_xor(partial, o);
            sc[q] = partial * 0.0625f;   // scale = 256^-0.5
        }
        float mx = sc[0];
        #pragma unroll
        for (int q = 1; q < 8; q++) mx = fmaxf(mx, sc[q]);
        float e[8]; float denom = 0.f;
        #pragma unroll
        for (int q = 0; q < 8; q++) { e[q] = expf(sc[q] - mx); denom += e[q]; }
        float inv = 1.0f / denom;
        float4 al = al_s[lane];
        float4 o4;
        o4.x = dv.x*al.x; o4.y = dv.y*al.y; o4.z = dv.z*al.z; o4.w = dv.w*al.w;
        #pragma unroll
        for (int q = 0; q < 8; q++) {
            float wq = e[q]*inv;
            float4 tv = t_s[q*64 + lane];
            o4.x += wq*tv.x; o4.y += wq*tv.y; o4.z += wq*tv.z; o4.w += wq*tv.w;
        }
        ((float4*)out)[p*64 + lane] = o4;
    }
}

// ---------------- NHWC -> NCHW ----------------
__global__ void nhwc_to_nchw_kernel(const float* __restrict__ in, float* __restrict__ out) {
    int b = blockIdx.z;
    int c0 = blockIdx.y*32, s0 = blockIdx.x*32;
    __shared__ float tile[32][33];
    int tx = threadIdx.x, ty = threadIdx.y;
    #pragma unroll
    for (int r = 0; r < 4; r++) {
        int sl = ty + 8*r;
        tile[tx][sl] = in[(b*HWs + s0 + sl)*CC + c0 + tx];
    }
    __syncthreads();
    #pragma unroll
    for (int r = 0; r < 4; r++) {
        int cl = ty + 8*r;
        out[(b*CC + c0 + cl)*HWs + s0 + tx] = tile[cl][tx];
    }
}

extern "C" void kernel_launch(void* const* d_in, const int* in_sizes, int n_in,
                              void* d_out, int out_size, void* d_ws, size_t ws_size,
                              hipStream_t stream) {
    const float* image_embed = (const float*)d_in[0];
    const float* inter_p     = (const float*)d_in[1];
    const float* intra_p     = (const float*)d_in[2];
    const float* masks       = (const float*)d_in[3];
    const float* proj_w      = (const float*)d_in[4];
    const float* proj_b      = (const float*)d_in[5];
    const float* lin_w       = (const float*)d_in[6];
    const float* lin_b       = (const float*)d_in[7];
    const float* tok_g       = (const float*)d_in[8];
    const float* tok_b       = (const float*)d_in[9];
    const float* alpha       = (const float*)d_in[10];
    const float* in_w        = (const float*)d_in[11];
    const float* in_b        = (const float*)d_in[12];
    const float* off0_w      = (const float*)d_in[13];
    const float* off0_b      = (const float*)d_in[14];
    const float* dw0_w       = (const float*)d_in[15];
    const float* dw0_b       = (const float*)d_in[16];
    const float* off1_w      = (const float*)d_in[17];
    const float* off1_b      = (const float*)d_in[18];
    const float* dw1_w       = (const float*)d_in[19];
    const float* dw1_b       = (const float*)d_in[20];
    const float* cv_w        = (const float*)d_in[21];
    const float* cv_b        = (const float*)d_in[22];
    const float* ln_g        = (const float*)d_in[23];
    const float* ln_b        = (const float*)d_in[24];
    const float* op0_w       = (const float*)d_in[25];
    const float* op0_b       = (const float*)d_in[26];
    const float* op1_w       = (const float*)d_in[27];
    const float* op1_b       = (const float*)d_in[28];
    const float* op2_w       = (const float*)d_in[29];
    const float* op2_b       = (const float*)d_in[30];
    const float* out0_w      = (const float*)d_in[31];
    const float* out0_b      = (const float*)d_in[32];
    const float* out1_w      = (const float*)d_in[33];
    const float* out1_b      = (const float*)d_in[34];
    (void)ws_size; (void)in_sizes; (void)n_in; (void)out_size;

    float* ws = (float*)d_ws;
    const size_t BIG = (size_t)PP * CC;     // 16,777,216 floats (64 MiB)
    // 3 big buffers in ws; d_out doubles as the 4th scratch buffer (D).
    float* A   = ws;                        // img -> xln -> o(NHWC)
    float* Bb  = A + BIG;                   // x -> y0 -> attn
    float* Cb  = Bb + BIG;                  // a1 -> a -> y1 -> o0
    float* D   = (float*)d_out;             // a2 -> dense -> final NCHW out
    float* OFF = Cb + BIG;                  // [P][27]
    float* TOK = OFF + (size_t)PP*27;       // [16][8][256]
    float* WT0 = TOK + BB*QQ*CC;
    float* WT1 = WT0 + 9*27*256;
    float* DWT0 = WT1 + 9*27*256;
    float* DWT1 = DWT0 + 9*256;
    float* OP1T = DWT1 + 9*256;
    // total ws: 3*BIG + 1,769,472 + 32,768 + 2*62,208 + 3*2,304 floats ~= 199.4 MiB

    // prep + token (tiny)
    prep_weights_kernel<<<(9*27*256 + 255)/256, 256, 0, stream>>>(
        off0_w, off1_w, dw0_w, dw1_w, op1_w, WT0, WT1, DWT0, DWT1, OP1T);
    token_kernel<<<BB*QQ, 256, 0, stream>>>(inter_p, intra_p, proj_w, proj_b,
                                            lin_w, lin_b, tok_g, tok_b, TOK);
    // img = ie*(1+pe) -> NHWC
    img_pe_kernel<<<dim3(HWs/32, CC/32, BB), dim3(32,8), 0, stream>>>(image_embed, intra_p, masks, A);
    // x = gelu(conv1x1(img))
    conv1x1_kernel<256,256,1,false><<<PP/64, 256, 0, stream>>>(A, in_w, in_b, nullptr, Bb);
    // deform block 1 (dil=1)
    off_conv_kernel<1><<<BB*HH, 256, 0, stream>>>(Bb, WT0, off0_b, OFF);
    deform_kernel<1><<<BB*HH, 256, 0, stream>>>(Bb, OFF, DWT0, dw0_b, Cb);
    // deform block 2 (dil=3)
    off_conv_kernel<3><<<BB*HH, 256, 0, stream>>>(Cb, WT1, off1_b, OFF);
    deform_kernel<3><<<BB*HH, 256, 0, stream>>>(Cb, OFF, DWT1, dw1_b, D);
    // a = conv1x1(a2)
    conv1x1_kernel<256,256,0,false><<<PP/64, 256, 0, stream>>>(D, cv_w, cv_b, nullptr, Cb);
    // x = LN2d(x*a + img)  (in-place on A is safe: each thread reads/writes its own p)
    gate_ln_kernel<<<PP/4, 256, 0, stream>>>(Bb, Cb, A, ln_g, ln_b, A);
    // y = conv1x1(x)
    conv1x1_kernel<256,256,0,false><<<PP/64, 256, 0, stream>>>(A, op0_w, op0_b, nullptr, Bb);
    // y = gelu(dw3x3(y))
    dw3x3_kernel<<<PP*64/256, 256, 0, stream>>>(Bb, OP1T, op1_b, Cb);
    // dense = conv1x1(y) + x
    conv1x1_kernel<256,256,0,true><<<PP/64, 256, 0, stream>>>(Cb, op2_w, op2_b, A, D);
    // attn = softmax-xattn(dense, t) + dense*alpha
    attn_kernel<<<BB*HH, 256, 0, stream>>>(D, TOK, alpha, Bb);
    // o = gelu(conv1x1_128(attn))
    conv1x1_kernel<256,128,1,false><<<PP/64, 256, 0, stream>>>(Bb, out0_w, out0_b, nullptr, Cb);
    // o = conv1x1(o) -> NHWC into A
    conv1x1_kernel<128,256,0,false><<<PP/64, 256, 0, stream>>>(Cb, out1_w, out1_b, nullptr, A);
    // NHWC -> NCHW final output
    nhwc_to_nchw_kernel<<<dim3(HWs/32, CC/32, BB), dim3(32,8), 0, stream>>>(A, (float*)d_out);
}

// Round 3
// 3328.601 us; speedup vs baseline: 1.1956x; 1.1956x over previous
//
#include <hip/hip_runtime.h>
#include <math.h>

#define BB 16
#define CC 256
#define HH 64
#define WW 64
#define HWs 4096
#define PP 65536   // BB*HWs
#define QQ 8
#define NN 9

__device__ __forceinline__ float gelu_f(float x) {
    return 0.5f * x * (1.0f + erff(x * 0.70710678118654752f));
}

// ---------------- weight prep ----------------
// wt[tap][k][ci]  <- off_w[k][ci][tap]   (27,256,3,3) -> (9,27,256)
// dwt[tap][c]     <- dw_w[c][0][tap]     (256,1,3,3)  -> (9,256)
// W4[k4][co]      <- float4(W[co][4k4..4k4+3])  (coalesced conv1x1 weights)
__global__ void prep_weights_kernel(const float* __restrict__ off0_w, const float* __restrict__ off1_w,
                                    const float* __restrict__ dw0_w, const float* __restrict__ dw1_w,
                                    const float* __restrict__ op1_w,
                                    const float* __restrict__ in_w, const float* __restrict__ cv_w,
                                    const float* __restrict__ op0_w, const float* __restrict__ op2_w,
                                    const float* __restrict__ out0_w, const float* __restrict__ out1_w,
                                    float* __restrict__ wt0, float* __restrict__ wt1,
                                    float* __restrict__ dwt0, float* __restrict__ dwt1,
                                    float* __restrict__ op1t,
                                    float4* __restrict__ w4_in, float4* __restrict__ w4_cv,
                                    float4* __restrict__ w4_op0, float4* __restrict__ w4_op2,
                                    float4* __restrict__ w4_out0, float4* __restrict__ w4_out1) {
    int i = blockIdx.x * 256 + threadIdx.x;
    if (i < 9*27*256) {
        int ci = i & 255;
        int k = (i >> 8) % 27;
        int tap = i / (27*256);
        wt0[i] = off0_w[(k*256 + ci)*9 + tap];
        wt1[i] = off1_w[(k*256 + ci)*9 + tap];
    }
    if (i < 9*256) {
        int c = i & 255;
        int tap = i >> 8;
        dwt0[i] = dw0_w[c*9 + tap];
        dwt1[i] = dw1_w[c*9 + tap];
        op1t[i] = op1_w[c*9 + tap];
    }
    if (i < 64*256) {   // CI=256, CO=256 weights: W4[k4*256+co]
        int co = i & 255;
        int k4 = i >> 8;
        w4_in[i]  = make_float4(in_w[co*256+4*k4],  in_w[co*256+4*k4+1],  in_w[co*256+4*k4+2],  in_w[co*256+4*k4+3]);
        w4_cv[i]  = make_float4(cv_w[co*256+4*k4],  cv_w[co*256+4*k4+1],  cv_w[co*256+4*k4+2],  cv_w[co*256+4*k4+3]);
        w4_op0[i] = make_float4(op0_w[co*256+4*k4], op0_w[co*256+4*k4+1], op0_w[co*256+4*k4+2], op0_w[co*256+4*k4+3]);
        w4_op2[i] = make_float4(op2_w[co*256+4*k4], op2_w[co*256+4*k4+1], op2_w[co*256+4*k4+2], op2_w[co*256+4*k4+3]);
    }
    if (i < 64*128) {   // out0: CI=256, CO=128: W4[k4*128+co]
        int co = i & 127;
        int k4 = i >> 7;
        w4_out0[i] = make_float4(out0_w[co*256+4*k4], out0_w[co*256+4*k4+1], out0_w[co*256+4*k4+2], out0_w[co*256+4*k4+3]);
    }
    if (i < 32*256) {   // out1: CI=128, CO=256: W4[k4*256+co]
        int co = i & 255;
        int k4 = i >> 8;
        w4_out1[i] = make_float4(out1_w[co*128+4*k4], out1_w[co*128+4*k4+1], out1_w[co*128+4*k4+2], out1_w[co*128+4*k4+3]);
    }
}

// ---------------- token path ----------------
__global__ void token_kernel(const float* __restrict__ inter, const float* __restrict__ intra,
                             const float* __restrict__ proj_w, const float* __restrict__ proj_b,
                             const float* __restrict__ lin_w, const float* __restrict__ lin_b,
                             const float* __restrict__ tok_g, const float* __restrict__ tok_b,
                             float* __restrict__ t_out) {
    int bq = blockIdx.x;
    int b = bq >> 3, q = bq & 7;
    int c = threadIdx.x;
    __shared__ float inter_s[256];
    __shared__ float pt_s[9];
    __shared__ float g_s[256];
    __shared__ float red[256];
    __shared__ float stat[2];
    inter_s[c] = inter[(b*QQ + q)*CC + c];
    __syncthreads();
    for (int n = 0; n < 9; n++) {
        red[c] = inter_s[c] * intra[(b*NN + n)*CC + c];
        __syncthreads();
        for (int s = 128; s > 0; s >>= 1) {
            if (c < s) red[c] += red[c + s];
            __syncthreads();
        }
        if (c == 0) pt_s[n] = red[0];
        __syncthreads();
    }
    float u = proj_b[c];
    for (int k = 0; k < 256; k++) u += inter_s[k] * proj_w[k*CC + c];
    for (int n = 0; n < 9; n++) u += pt_s[n] * proj_w[(256 + n)*CC + c];
    g_s[c] = gelu_f(u);
    __syncthreads();
    float v = lin_b[c];
    for (int k = 0; k < 256; k++) v += g_s[k] * lin_w[k*CC + c];
    red[c] = v;
    __syncthreads();
    for (int s = 128; s > 0; s >>= 1) { if (c < s) red[c] += red[c + s]; __syncthreads(); }
    if (c == 0) stat[0] = red[0] * (1.0f/256.0f);
    __syncthreads();
    float m = stat[0];
    red[c] = (v - m)*(v - m);
    __syncthreads();
    for (int s = 128; s > 0; s >>= 1) { if (c < s) red[c] += red[c + s]; __syncthreads(); }
    if (c == 0) stat[1] = red[0] * (1.0f/256.0f);
    __syncthreads();
    float var = stat[1];
    float r = rsqrtf(var + 1e-5f);
    t_out[(b*QQ + q)*CC + c] = (v - m) * r * tok_g[c] + tok_b[c];
}

// ---------------- img = ie*(1+pe), NCHW -> NHWC transpose ----------------
__global__ void img_pe_kernel(const float* __restrict__ ie, const float* __restrict__ intra,
                              const float* __restrict__ masks, float* __restrict__ img) {
    int b = blockIdx.z;
    int c0 = blockIdx.y * 32;
    int s0 = blockIdx.x * 32;
    __shared__ float tile[32][33];
    __shared__ float intra_s[9][32];
    __shared__ float mask_s[9][32];
    int tx = threadIdx.x, ty = threadIdx.y;
    int t = ty*32 + tx;
    for (int i = t; i < 288; i += 256) {
        int n = i >> 5, j = i & 31;
        intra_s[n][j] = intra[(b*NN + n)*CC + c0 + j];
        mask_s[n][j]  = masks[(b*NN + n)*HWs + s0 + j];
    }
    __syncthreads();
    #pragma unroll
    for (int r = 0; r < 4; r++) {
        int cl = ty + 8*r;
        float val = ie[(b*CC + c0 + cl)*HWs + s0 + tx];
        float pe = 0.f;
        #pragma unroll
        for (int n = 0; n < 9; n++) pe += intra_s[n][cl] * mask_s[n][tx];
        tile[cl][tx] = val * (1.0f + pe);
    }
    __syncthreads();
    #pragma unroll
    for (int r = 0; r < 4; r++) {
        int sl = ty + 8*r;
        img[(b*HWs + s0 + sl)*CC + c0 + tx] = tile[tx][sl];
    }
}

// ---------------- generic NHWC 1x1 conv (GEMM), coalesced W4 weights ----------------
// Wt layout: float4 W4[k4][CO], W4[k4*CO+co] = W[co][4k4..4k4+3]
template<int CI, int CO, int ACT, bool RES>
__global__ void __launch_bounds__(256) conv1x1_kernel(const float* __restrict__ in, const float4* __restrict__ Wf,
        const float* __restrict__ bias, const float* __restrict__ res, float* __restrict__ out) {
    constexpr int CI4 = CI/4;
    constexpr int CO4 = CO/4;
    constexpr int NCOG = CO/4;       // co-groups of 4
    constexpr int PG = 256 / NCOG;   // p-groups
    constexpr int PPT = 64 / PG;     // rows per thread
    __shared__ float4 in_s[64*CI4];
    int t = threadIdx.x;
    int p0 = blockIdx.x * 64;
    const float4* inf = (const float4*)in;
    for (int i = t; i < 64*CI4; i += 256) in_s[i] = inf[p0*CI4 + i];
    __syncthreads();
    int cog = t % NCOG;
    int pg = t / NCOG;
    int co = cog * 4;
    float acc[4][PPT];
    #pragma unroll
    for (int j = 0; j < 4; j++)
        #pragma unroll
        for (int pp = 0; pp < PPT; pp++) acc[j][pp] = 0.f;
    for (int k = 0; k < CI4; k++) {
        float4 w0 = Wf[k*CO + co+0];
        float4 w1 = Wf[k*CO + co+1];
        float4 w2 = Wf[k*CO + co+2];
        float4 w3 = Wf[k*CO + co+3];
        #pragma unroll
        for (int pp = 0; pp < PPT; pp++) {
            float4 xv = in_s[(pg*PPT + pp)*CI4 + k];
            acc[0][pp] += xv.x*w0.x + xv.y*w0.y + xv.z*w0.z + xv.w*w0.w;
            acc[1][pp] += xv.x*w1.x + xv.y*w1.y + xv.z*w1.z + xv.w*w1.w;
            acc[2][pp] += xv.x*w2.x + xv.y*w2.y + xv.z*w2.z + xv.w*w2.w;
            acc[3][pp] += xv.x*w3.x + xv.y*w3.y + xv.z*w3.z + xv.w*w3.w;
        }
    }
    float b0 = bias[co], b1 = bias[co+1], b2 = bias[co+2], b3 = bias[co+3];
    #pragma unroll
    for (int pp = 0; pp < PPT; pp++) {
        int p = p0 + pg*PPT + pp;
        float4 v;
        v.x = acc[0][pp] + b0; v.y = acc[1][pp] + b1; v.z = acc[2][pp] + b2; v.w = acc[3][pp] + b3;
        if (ACT == 1) { v.x = gelu_f(v.x); v.y = gelu_f(v.y); v.z = gelu_f(v.z); v.w = gelu_f(v.w); }
        if (RES) {
            float4 rv = ((const float4*)res)[p*CO4 + cog];
            v.x += rv.x; v.y += rv.y; v.z += rv.z; v.w += rv.w;
        }
        ((float4*)out)[p*CO4 + cog] = v;
    }
}

// ---------------- 3x3 offset conv (27 out channels), NHWC in, [p][27] out ----------------
// one block per (b,h) image row; wt is pre-transposed [tap][k][ci]
// kq is readfirstlane-uniform so weight fetches become scalar (s_load) ops.
template<int DIL>
__global__ void __launch_bounds__(256) off_conv_kernel(const float* __restrict__ x, const float* __restrict__ wt,
        const float* __restrict__ bias, float* __restrict__ off) {
    __shared__ float4 xs[4096];  // xor-swizzled: value (w,c4) at xs[c4*64 + (w^c4)]
    int bh = blockIdx.x;
    int b = bh >> 6, h = bh & 63;
    int t = threadIdx.x;
    int w = t & 63;
    int kq = __builtin_amdgcn_readfirstlane(t >> 6);   // wave-uniform 0..3
    const int kbase = kq * 7;
    float acc[7];
    #pragma unroll
    for (int j = 0; j < 7; j++) acc[j] = 0.f;
    const float4* wtf = (const float4*)wt;
    for (int ki = 0; ki < 3; ki++) {
        int hrow = h + (ki - 1)*DIL;
        __syncthreads();
        if (hrow >= 0 && hrow < 64) {
            const float4* row = (const float4*)(x + ((size_t)(b*64 + hrow)*64) * 256);
            for (int i = t; i < 4096; i += 256) {
                int ww = i >> 6, c4 = i & 63;
                xs[c4*64 + (ww ^ c4)] = row[ww*64 + c4];
            }
        } else {
            float4 z = make_float4(0.f,0.f,0.f,0.f);
            for (int i = t; i < 4096; i += 256) xs[i] = z;
        }
        __syncthreads();
        for (int kj = 0; kj < 3; kj++) {
            int wcol = w + (kj - 1)*DIL;
            if (wcol < 0 || wcol >= 64) continue;
            const float4* wtap = wtf + ((size_t)((ki*3 + kj)*27 + kbase))*64;
            for (int k4 = 0; k4 < 64; k4++) {
                float4 xv = xs[k4*64 + (wcol ^ k4)];
                #pragma unroll
                for (int j = 0; j < 7; j++) {
                    if (kbase + j < 27) {
                        float4 wv = wtap[j*64 + k4];
                        acc[j] += xv.x*wv.x + xv.y*wv.y + xv.z*wv.z + xv.w*wv.w;
                    }
                }
            }
        }
    }
    int p = (b*64 + h)*64 + w;
    #pragma unroll
    for (int j = 0; j < 7; j++) {
        if (kbase + j < 27) off[(size_t)p*27 + kbase + j] = acc[j] + bias[kbase + j];
    }
}

// ---------------- modulated deformable depthwise 3x3 ----------------
template<int DIL>
__global__ void __launch_bounds__(256) deform_kernel(const float* __restrict__ src, const float* __restrict__ off,
        const float* __restrict__ dwt, const float* __restrict__ dwb, float* __restrict__ out) {
    int bh = blockIdx.x;
    int b = bh >> 6, h = bh & 63;
    int t = threadIdx.x;
    int c4 = t & 63;
    int ps = t >> 6;
    float4 dwv[9];
    #pragma unroll
    for (int kk = 0; kk < 9; kk++) dwv[kk] = ((const float4*)dwt)[kk*64 + c4];
    float4 bv = ((const float4*)dwb)[c4];
    const float4* srcf = (const float4*)src;
    for (int i = 0; i < 16; i++) {
        int w = ps*16 + i;
        int p = (b*64 + h)*64 + w;
        const float* op = off + (size_t)p*27;
        float4 acc = make_float4(0.f,0.f,0.f,0.f);
        #pragma unroll
        for (int kk = 0; kk < 9; kk++) {
            int ki = kk / 3, kj = kk % 3;
            float ox = op[kk];
            float oy = op[9 + kk];
            float mm = op[18 + kk];
            mm = 1.0f / (1.0f + expf(-mm));
            float py = (float)(h - DIL + ki*DIL) + oy;
            float px = (float)(w - DIL + kj*DIL) + ox;
            float y0f = floorf(py), x0f = floorf(px);
            float wy = py - y0f, wx = px - x0f;
            int y0 = (int)y0f, x0 = (int)x0f;
            int y1 = y0 + 1, x1 = x0 + 1;
            float w00 = (1.f - wy)*(1.f - wx), w01 = (1.f - wy)*wx;
            float w10 = wy*(1.f - wx), w11 = wy*wx;
            float4 s = make_float4(0.f,0.f,0.f,0.f);
            bool xv0 = (x0 >= 0) && (x0 < 64);
            bool xv1 = (x1 >= 0) && (x1 < 64);
            if (y0 >= 0 && y0 < 64) {
                const float4* r0 = srcf + (size_t)((b*64 + y0)*64) * 64;
                if (xv0) { float4 v = r0[x0*64 + c4]; s.x += v.x*w00; s.y += v.y*w00; s.z += v.z*w00; s.w += v.w*w00; }
                if (xv1) { float4 v = r0[x1*64 + c4]; s.x += v.x*w01; s.y += v.y*w01; s.z += v.z*w01; s.w += v.w*w01; }
            }
            if (y1 >= 0 && y1 < 64) {
                const float4* r1 = srcf + (size_t)((b*64 + y1)*64) * 64;
                if (xv0) { float4 v = r1[x0*64 + c4]; s.x += v.x*w10; s.y += v.y*w10; s.z += v.z*w10; s.w += v.w*w10; }
                if (xv1) { float4 v = r1[x1*64 + c4]; s.x += v.x*w11; s.y += v.y*w11; s.z += v.z*w11; s.w += v.w*w11; }
            }
            acc.x += s.x * mm * dwv[kk].x;
            acc.y += s.y * mm * dwv[kk].y;
            acc.z += s.z * mm * dwv[kk].z;
            acc.w += s.w * mm * dwv[kk].w;
        }
        float4 o4;
        o4.x = acc.x + bv.x; o4.y = acc.y + bv.y; o4.z = acc.z + bv.z; o4.w = acc.w + bv.w;
        ((float4*)out)[(size_t)p*64 + c4] = o4;
    }
}

// ---------------- xg = x*a + img; LayerNorm over C ----------------
__global__ void __launch_bounds__(256) gate_ln_kernel(const float* __restrict__ x, const float* __restrict__ a,
        const float* __restrict__ img, const float* __restrict__ g, const float* __restrict__ bb,
        float* __restrict__ out) {
    int t = threadIdx.x;
    int lane = t & 63;
    int wv = t >> 6;
    int p = blockIdx.x*4 + wv;
    float4 xv = ((const float4*)x)[p*64 + lane];
    float4 av = ((const float4*)a)[p*64 + lane];
    float4 iv = ((const float4*)img)[p*64 + lane];
    float4 v;
    v.x = xv.x*av.x + iv.x; v.y = xv.y*av.y + iv.y;
    v.z = xv.z*av.z + iv.z; v.w = xv.w*av.w + iv.w;
    float s = v.x + v.y + v.z + v.w;
    float s2 = v.x*v.x + v.y*v.y + v.z*v.z + v.w*v.w;
    #pragma unroll
    for (int o = 1; o < 64; o <<= 1) { s += __shfl_xor(s, o); s2 += __shfl_xor(s2, o); }
    float m = s * (1.f/256.f);
    float var = s2 * (1.f/256.f) - m*m;
    float r = rsqrtf(var + 1e-5f);
    float4 gv = ((const float4*)g)[lane];
    float4 bv = ((const float4*)bb)[lane];
    float4 o4;
    o4.x = (v.x - m)*r*gv.x + bv.x;
    o4.y = (v.y - m)*r*gv.y + bv.y;
    o4.z = (v.z - m)*r*gv.z + bv.z;
    o4.w = (v.w - m)*r*gv.w + bv.w;
    ((float4*)out)[p*64 + lane] = o4;
}

// ---------------- depthwise 3x3 pad=1 + gelu (NHWC) ----------------
__global__ void __launch_bounds__(256) dw3x3_kernel(const float* __restrict__ in, const float* __restrict__ wt,
        const float* __restrict__ bias, float* __restrict__ out) {
    int gid = blockIdx.x*256 + threadIdx.x;
    int c4 = gid & 63;
    int p = gid >> 6;
    int w = p & 63;
    int h = (p >> 6) & 63;
    int b = p >> 12;
    float4 acc = ((const float4*)bias)[c4];
    #pragma unroll
    for (int ki = 0; ki < 3; ki++) {
        int hh = h + ki - 1;
        if (hh < 0 || hh >= 64) continue;
        #pragma unroll
        for (int kj = 0; kj < 3; kj++) {
            int wwp = w + kj - 1;
            if (wwp < 0 || wwp >= 64) continue;
            float4 v = ((const float4*)in)[((b*64 + hh)*64 + wwp)*64 + c4];
            float4 wv = ((const float4*)wt)[(ki*3 + kj)*64 + c4];
            acc.x += v.x*wv.x; acc.y += v.y*wv.y; acc.z += v.z*wv.z; acc.w += v.w*wv.w;
        }
    }
    acc.x = gelu_f(acc.x); acc.y = gelu_f(acc.y); acc.z = gelu_f(acc.z); acc.w = gelu_f(acc.w);
    ((float4*)out)[p*64 + c4] = acc;
}

// ---------------- 8-token cross attention + alpha residual ----------------
__global__ void __launch_bounds__(256) attn_kernel(const float* __restrict__ dense, const float* __restrict__ tok,
        const float* __restrict__ alpha, float* __restrict__ out) {
    __shared__ float4 t_s[8*64];
    __shared__ float4 al_s[64];
    int bh = blockIdx.x;
    int b = bh >> 6, h = bh & 63;
    int t = threadIdx.x;
    for (int i = t; i < 512; i += 256) t_s[i] = ((const float4*)tok)[b*512 + i];
    if (t < 64) al_s[t] = ((const float4*)alpha)[t];
    __syncthreads();
    int lane = t & 63, ps = t >> 6;
    for (int i = 0; i < 16; i++) {
        int w = ps*16 + i;
        int p = (b*64 + h)*64 + w;
        float4 dv = ((const float4*)dense)[p*64 + lane];
        float sc[8];
        #pragma unroll
        for (int q = 0; q < 8; q++) {
            float4 tv = t_s[q*64 + lane];
            float partial = dv.x*tv.x + dv.y*tv.y + dv.z*tv.z + dv.w*tv.w;
            #pragma unroll
            for (int o = 1; o < 64; o <<= 1) partial += __shfl_xor(partial, o);
            sc[q] = partial * 0.0625f;   // scale = 256^-0.5
        }
        float mx = sc[0];
        #pragma unroll
        for (int q = 1; q < 8; q++) mx = fmaxf(mx, sc[q]);
        float e[8]; float denom = 0.f;
        #pragma unroll
        for (int q = 0; q < 8; q++) { e[q] = expf(sc[q] - mx); denom += e[q]; }
        float inv = 1.0f / denom;
        float4 al = al_s[lane];
        float4 o4;
        o4.x = dv.x*al.x; o4.y = dv.y*al.y; o4.z = dv.z*al.z; o4.w = dv.w*al.w;
        #pragma unroll
        for (int q = 0; q < 8; q++) {
            float wq = e[q]*inv;
            float4 tv = t_s[q*64 + lane];
            o4.x += wq*tv.x; o4.y += wq*tv.y; o4.z += wq*tv.z; o4.w += wq*tv.w;
        }
        ((float4*)out)[p*64 + lane] = o4;
    }
}

// ---------------- NHWC -> NCHW ----------------
__global__ void nhwc_to_nchw_kernel(const float* __restrict__ in, float* __restrict__ out) {
    int b = blockIdx.z;
    int c0 = blockIdx.y*32, s0 = blockIdx.x*32;
    __shared__ float tile[32][33];
    int tx = threadIdx.x, ty = threadIdx.y;
    #pragma unroll
    for (int r = 0; r < 4; r++) {
        int sl = ty + 8*r;
        tile[tx][sl] = in[(b*HWs + s0 + sl)*CC + c0 + tx];
    }
    __syncthreads();
    #pragma unroll
    for (int r = 0; r < 4; r++) {
        int cl = ty + 8*r;
        out[(b*CC + c0 + cl)*HWs + s0 + tx] = tile[cl][tx];
    }
}

extern "C" void kernel_launch(void* const* d_in, const int* in_sizes, int n_in,
                              void* d_out, int out_size, void* d_ws, size_t ws_size,
                              hipStream_t stream) {
    const float* image_embed = (const float*)d_in[0];
    const float* inter_p     = (const float*)d_in[1];
    const float* intra_p     = (const float*)d_in[2];
    const float* masks       = (const float*)d_in[3];
    const float* proj_w      = (const float*)d_in[4];
    const float* proj_b      = (const float*)d_in[5];
    const float* lin_w       = (const float*)d_in[6];
    const float* lin_b       = (const float*)d_in[7];
    const float* tok_g       = (const float*)d_in[8];
    const float* tok_b       = (const float*)d_in[9];
    const float* alpha       = (const float*)d_in[10];
    const float* in_w        = (const float*)d_in[11];
    const float* in_b        = (const float*)d_in[12];
    const float* off0_w      = (const float*)d_in[13];
    const float* off0_b      = (const float*)d_in[14];
    const float* dw0_w       = (const float*)d_in[15];
    const float* dw0_b       = (const float*)d_in[16];
    const float* off1_w      = (const float*)d_in[17];
    const float* off1_b      = (const float*)d_in[18];
    const float* dw1_w       = (const float*)d_in[19];
    const float* dw1_b       = (const float*)d_in[20];
    const float* cv_w        = (const float*)d_in[21];
    const float* cv_b        = (const float*)d_in[22];
    const float* ln_g        = (const float*)d_in[23];
    const float* ln_b        = (const float*)d_in[24];
    const float* op0_w       = (const float*)d_in[25];
    const float* op0_b       = (const float*)d_in[26];
    const float* op1_w       = (const float*)d_in[27];
    const float* op1_b       = (const float*)d_in[28];
    const float* op2_w       = (const float*)d_in[29];
    const float* op2_b       = (const float*)d_in[30];
    const float* out0_w      = (const float*)d_in[31];
    const float* out0_b      = (const float*)d_in[32];
    const float* out1_w      = (const float*)d_in[33];
    const float* out1_b      = (const float*)d_in[34];
    (void)ws_size; (void)in_sizes; (void)n_in; (void)out_size;

    float* ws = (float*)d_ws;
    const size_t BIG = (size_t)PP * CC;     // 16,777,216 floats (64 MiB)
    float* A   = ws;                        // img -> xln -> o(NHWC)
    float* Bb  = A + BIG;                   // x -> y0 -> attn
    float* Cb  = Bb + BIG;                  // a1 -> a -> y1 -> o0
    float* D   = (float*)d_out;             // a2 -> dense -> final NCHW out
    float* OFF = Cb + BIG;                  // [P][27]
    float* TOK = OFF + (size_t)PP*27;       // [16][8][256]
    float* WT0 = TOK + BB*QQ*CC;
    float* WT1 = WT0 + 9*27*256;
    float* DWT0 = WT1 + 9*27*256;
    float* DWT1 = DWT0 + 9*256;
    float* OP1T = DWT1 + 9*256;
    float4* W4_IN   = (float4*)(OP1T + 9*256);
    float4* W4_CV   = W4_IN + 64*256;
    float4* W4_OP0  = W4_CV + 64*256;
    float4* W4_OP2  = W4_OP0 + 64*256;
    float4* W4_OUT0 = W4_OP2 + 64*256;
    float4* W4_OUT1 = W4_OUT0 + 64*128;
    // ws total ~= 200.7 MiB

    prep_weights_kernel<<<(9*27*256 + 255)/256, 256, 0, stream>>>(
        off0_w, off1_w, dw0_w, dw1_w, op1_w,
        in_w, cv_w, op0_w, op2_w, out0_w, out1_w,
        WT0, WT1, DWT0, DWT1, OP1T,
        W4_IN, W4_CV, W4_OP0, W4_OP2, W4_OUT0, W4_OUT1);
    token_kernel<<<BB*QQ, 256, 0, stream>>>(inter_p, intra_p, proj_w, proj_b,
                                            lin_w, lin_b, tok_g, tok_b, TOK);
    // img = ie*(1+pe) -> NHWC
    img_pe_kernel<<<dim3(HWs/32, CC/32, BB), dim3(32,8), 0, stream>>>(image_embed, intra_p, masks, A);
    // x = gelu(conv1x1(img))
    conv1x1_kernel<256,256,1,false><<<PP/64, 256, 0, stream>>>(A, W4_IN, in_b, nullptr, Bb);
    // deform block 1 (dil=1)
    off_conv_kernel<1><<<BB*HH, 256, 0, stream>>>(Bb, WT0, off0_b, OFF);
    deform_kernel<1><<<BB*HH, 256, 0, stream>>>(Bb, OFF, DWT0, dw0_b, Cb);
    // deform block 2 (dil=3)
    off_conv_kernel<3><<<BB*HH, 256, 0, stream>>>(Cb, WT1, off1_b, OFF);
    deform_kernel<3><<<BB*HH, 256, 0, stream>>>(Cb, OFF, DWT1, dw1_b, D);
    // a = conv1x1(a2)
    conv1x1_kernel<256,256,0,false><<<PP/64, 256, 0, stream>>>(D, W4_CV, cv_b, nullptr, Cb);
    // x = LN2d(x*a + img)
    gate_ln_kernel<<<PP/4, 256, 0, stream>>>(Bb, Cb, A, ln_g, ln_b, A);
    // y = conv1x1(x)
    conv1x1_kernel<256,256,0,false><<<PP/64, 256, 0, stream>>>(A, W4_OP0, op0_b, nullptr, Bb);
    // y = gelu(dw3x3(y))
    dw3x3_kernel<<<PP*64/256, 256, 0, stream>>>(Bb, OP1T, op1_b, Cb);
    // dense = conv1x1(y) + x
    conv1x1_kernel<256,256,0,true><<<PP/64, 256, 0, stream>>>(Cb, W4_OP2, op2_b, A, D);
    // attn = softmax-xattn(dense, t) + dense*alpha
    attn_kernel<<<BB*HH, 256, 0, stream>>>(D, TOK, alpha, Bb);
    // o = gelu(conv1x1_128(attn))
    conv1x1_kernel<256,128,1,false><<<PP/64, 256, 0, stream>>>(Bb, W4_OUT0, out0_b, nullptr, Cb);
    // o = conv1x1(o) -> NHWC into A
    conv1x1_kernel<128,256,0,false><<<PP/64, 256, 0, stream>>>(Cb, W4_OUT1, out1_b, nullptr, A);
    // NHWC -> NCHW final output
    nhwc_to_nchw_kernel<<<dim3(HWs/32, CC/32, BB), dim3(32,8), 0, stream>>>(A, (float*)d_out);
}

// Round 4
// 1386.039 us; speedup vs baseline: 2.8712x; 2.4015x over previous
//
#include <hip/hip_runtime.h>
#include <math.h>

#define BB 16
#define CC 256
#define HH 64
#define WW 64
#define HWs 4096
#define PP 65536   // BB*HWs
#define QQ 8
#define NN 9

typedef _Float16 half8_t __attribute__((ext_vector_type(8)));
typedef _Float16 half4_t __attribute__((ext_vector_type(4)));
typedef float floatx4 __attribute__((ext_vector_type(4)));

__device__ __forceinline__ float gelu_f(float x) {
    return 0.5f * x * (1.0f + erff(x * 0.70710678118654752f));
}

// ---------------- weight prep ----------------
// dwt[tap][c] <- dw_w[c][0][tap]; op1t likewise (fp32, for depthwise kernels)
// wh_* : f16 copies of 1x1 conv weights, [co][ci] row-major
// whoff[tap][k(32,pad27)][ci] f16 for the offset convs
__global__ void prep_weights_kernel(const float* __restrict__ off0_w, const float* __restrict__ off1_w,
                                    const float* __restrict__ dw0_w, const float* __restrict__ dw1_w,
                                    const float* __restrict__ op1_w,
                                    const float* __restrict__ in_w, const float* __restrict__ cv_w,
                                    const float* __restrict__ op0_w, const float* __restrict__ op2_w,
                                    const float* __restrict__ out0_w, const float* __restrict__ out1_w,
                                    float* __restrict__ dwt0, float* __restrict__ dwt1,
                                    float* __restrict__ op1t,
                                    _Float16* __restrict__ wh_in, _Float16* __restrict__ wh_cv,
                                    _Float16* __restrict__ wh_op0, _Float16* __restrict__ wh_op2,
                                    _Float16* __restrict__ wh_out0, _Float16* __restrict__ wh_out1,
                                    _Float16* __restrict__ whoff0, _Float16* __restrict__ whoff1) {
    int i = blockIdx.x * 256 + threadIdx.x;
    if (i < 9*256) {
        int c = i & 255;
        int tap = i >> 8;
        dwt0[i] = dw0_w[c*9 + tap];
        dwt1[i] = dw1_w[c*9 + tap];
        op1t[i] = op1_w[c*9 + tap];
    }
    if (i < 65536) {            // [256][256] f16 direct casts
        wh_in[i]  = (_Float16)in_w[i];
        wh_cv[i]  = (_Float16)cv_w[i];
        wh_op0[i] = (_Float16)op0_w[i];
        wh_op2[i] = (_Float16)op2_w[i];
    }
    if (i < 32768) {            // out0: [128][256], out1: [256][128]
        wh_out0[i] = (_Float16)out0_w[i];
        wh_out1[i] = (_Float16)out1_w[i];
    }
    if (i < 9*32*256) {         // whoff[tap][k32][ci], zero-padded k>=27
        int ci = i & 255;
        int k32 = (i >> 8) & 31;
        int tap = i >> 13;
        float v0 = 0.f, v1 = 0.f;
        if (k32 < 27) {
            v0 = off0_w[(k32*256 + ci)*9 + tap];
            v1 = off1_w[(k32*256 + ci)*9 + tap];
        }
        whoff0[i] = (_Float16)v0;
        whoff1[i] = (_Float16)v1;
    }
}

// ---------------- token path ----------------
__global__ void token_kernel(const float* __restrict__ inter, const float* __restrict__ intra,
                             const float* __restrict__ proj_w, const float* __restrict__ proj_b,
                             const float* __restrict__ lin_w, const float* __restrict__ lin_b,
                             const float* __restrict__ tok_g, const float* __restrict__ tok_b,
                             float* __restrict__ t_out) {
    int bq = blockIdx.x;
    int b = bq >> 3, q = bq & 7;
    int c = threadIdx.x;
    __shared__ float inter_s[256];
    __shared__ float pt_s[9];
    __shared__ float g_s[256];
    __shared__ float red[256];
    __shared__ float stat[2];
    inter_s[c] = inter[(b*QQ + q)*CC + c];
    __syncthreads();
    for (int n = 0; n < 9; n++) {
        red[c] = inter_s[c] * intra[(b*NN + n)*CC + c];
        __syncthreads();
        for (int s = 128; s > 0; s >>= 1) {
            if (c < s) red[c] += red[c + s];
            __syncthreads();
        }
        if (c == 0) pt_s[n] = red[0];
        __syncthreads();
    }
    float u = proj_b[c];
    for (int k = 0; k < 256; k++) u += inter_s[k] * proj_w[k*CC + c];
    for (int n = 0; n < 9; n++) u += pt_s[n] * proj_w[(256 + n)*CC + c];
    g_s[c] = gelu_f(u);
    __syncthreads();
    float v = lin_b[c];
    for (int k = 0; k < 256; k++) v += g_s[k] * lin_w[k*CC + c];
    red[c] = v;
    __syncthreads();
    for (int s = 128; s > 0; s >>= 1) { if (c < s) red[c] += red[c + s]; __syncthreads(); }
    if (c == 0) stat[0] = red[0] * (1.0f/256.0f);
    __syncthreads();
    float m = stat[0];
    red[c] = (v - m)*(v - m);
    __syncthreads();
    for (int s = 128; s > 0; s >>= 1) { if (c < s) red[c] += red[c + s]; __syncthreads(); }
    if (c == 0) stat[1] = red[0] * (1.0f/256.0f);
    __syncthreads();
    float var = stat[1];
    float r = rsqrtf(var + 1e-5f);
    t_out[(b*QQ + q)*CC + c] = (v - m) * r * tok_g[c] + tok_b[c];
}

// ---------------- img = ie*(1+pe), NCHW -> NHWC transpose ----------------
__global__ void img_pe_kernel(const float* __restrict__ ie, const float* __restrict__ intra,
                              const float* __restrict__ masks, float* __restrict__ img) {
    int b = blockIdx.z;
    int c0 = blockIdx.y * 32;
    int s0 = blockIdx.x * 32;
    __shared__ float tile[32][33];
    __shared__ float intra_s[9][32];
    __shared__ float mask_s[9][32];
    int tx = threadIdx.x, ty = threadIdx.y;
    int t = ty*32 + tx;
    for (int i = t; i < 288; i += 256) {
        int n = i >> 5, j = i & 31;
        intra_s[n][j] = intra[(b*NN + n)*CC + c0 + j];
        mask_s[n][j]  = masks[(b*NN + n)*HWs + s0 + j];
    }
    __syncthreads();
    #pragma unroll
    for (int r = 0; r < 4; r++) {
        int cl = ty + 8*r;
        float val = ie[(b*CC + c0 + cl)*HWs + s0 + tx];
        float pe = 0.f;
        #pragma unroll
        for (int n = 0; n < 9; n++) pe += intra_s[n][cl] * mask_s[n][tx];
        tile[cl][tx] = val * (1.0f + pe);
    }
    __syncthreads();
    #pragma unroll
    for (int r = 0; r < 4; r++) {
        int sl = ty + 8*r;
        img[(b*HWs + s0 + sl)*CC + c0 + tx] = tile[tx][sl];
    }
}

// ---------------- MFMA 1x1 conv (GEMM) ----------------
// out[p,co] = RES?res: + act(bias + sum_ci in[p,ci]*W[co,ci])
// Wh: f16 [CO][CI] row-major. Block: 64 rows of p, full CO. 4 waves, wave wid
// covers co-strip [wid*CO/4, ...). f16 MFMA 16x16x32, fp32 accum.
template<int CI, int CO, int ACT, bool RES>
__global__ void __launch_bounds__(256) conv1x1_mfma(const float* __restrict__ in, const _Float16* __restrict__ Wh,
        const float* __restrict__ bias, const float* __restrict__ res, float* __restrict__ out) {
    constexpr int KS = CI/32;        // k-steps
    constexpr int NF = CO/64;        // n-frags per wave
    constexpr int LDR = CI + 8;      // halves per LDS row (+16B pad)
    __shared__ __align__(16) _Float16 a_lds[64*LDR];
    int t = threadIdx.x;
    int wid = t >> 6, lane = t & 63;
    int quad = lane >> 4, l16 = lane & 15;
    int p0 = blockIdx.x * 64;
    // stage 64 x CI fp32 -> f16 LDS
    const float4* inf = (const float4*)in + (size_t)p0*(CI/4);
    for (int i = t; i < 64*(CI/4); i += 256) {
        float4 v = inf[i];
        half4_t hv; hv[0]=(_Float16)v.x; hv[1]=(_Float16)v.y; hv[2]=(_Float16)v.z; hv[3]=(_Float16)v.w;
        int r = i/(CI/4), c4 = i%(CI/4);
        *(half4_t*)&a_lds[r*LDR + c4*4] = hv;
    }
    __syncthreads();
    int n0 = wid*(CO/4);
    floatx4 acc[4][NF];
    #pragma unroll
    for (int mf = 0; mf < 4; mf++)
        #pragma unroll
        for (int nf = 0; nf < NF; nf++)
            #pragma unroll
            for (int r = 0; r < 4; r++) acc[mf][nf][r] = 0.f;
    for (int ks = 0; ks < KS; ks++) {
        int k = ks*32 + quad*8;
        half8_t a[4];
        #pragma unroll
        for (int mf = 0; mf < 4; mf++)
            a[mf] = *(const half8_t*)&a_lds[(mf*16 + l16)*LDR + k];
        half8_t bfr[NF];
        #pragma unroll
        for (int nf = 0; nf < NF; nf++)
            bfr[nf] = *(const half8_t*)&Wh[(size_t)(n0 + nf*16 + l16)*CI + k];
        #pragma unroll
        for (int mf = 0; mf < 4; mf++)
            #pragma unroll
            for (int nf = 0; nf < NF; nf++)
                acc[mf][nf] = __builtin_amdgcn_mfma_f32_16x16x32_f16(a[mf], bfr[nf], acc[mf][nf], 0, 0, 0);
    }
    // epilogue: C/D col=lane&15 (co), row=quad*4+reg (p)
    #pragma unroll
    for (int nf = 0; nf < NF; nf++) {
        int co = n0 + nf*16 + l16;
        float bs = bias[co];
        #pragma unroll
        for (int mf = 0; mf < 4; mf++) {
            #pragma unroll
            for (int r = 0; r < 4; r++) {
                int p = p0 + mf*16 + quad*4 + r;
                float v = acc[mf][nf][r] + bs;
                if (ACT) v = gelu_f(v);
                if (RES) v += res[(size_t)p*CO + co];
                out[(size_t)p*CO + co] = v;
            }
        }
    }
}

// ---------------- MFMA 3x3 offset conv -> [p][27] ----------------
// GEMM: M=64 (one b,h row), N=32 (27 padded), K=3*3*256. Wave wid owns m-frag
// rows wid*16..+15. x staged per-ki as f16 row with +-3 zero margin in w.
template<int DIL>
__global__ void __launch_bounds__(256) off_conv_mfma(const float* __restrict__ x, const _Float16* __restrict__ Wh,
        const float* __restrict__ bias, float* __restrict__ off) {
    constexpr int LDR = 264;    // 256 + 16B pad, halves
    __shared__ __align__(16) _Float16 xs[70*LDR];   // w = -3..66 at idx w+3
    int bh = blockIdx.x;
    int b = bh >> 6, h = bh & 63;
    int t = threadIdx.x;
    int wid = t >> 6, lane = t & 63;
    int quad = lane >> 4, l16 = lane & 15;
    // zero the 6 margin rows once
    for (int i = t; i < 6*LDR; i += 256) {
        int r = i/LDR, c = i%LDR;
        int row = (r < 3) ? r : (64 + r);   // 0,1,2, 67,68,69
        xs[row*LDR + c] = (_Float16)0.f;
    }
    floatx4 acc[2];
    #pragma unroll
    for (int nf = 0; nf < 2; nf++)
        #pragma unroll
        for (int r = 0; r < 4; r++) acc[nf][r] = 0.f;
    for (int ki = 0; ki < 3; ki++) {
        int hrow = h + (ki - 1)*DIL;
        __syncthreads();
        if (hrow >= 0 && hrow < 64) {
            const float4* row = (const float4*)(x + ((size_t)(b*64 + hrow)*64) * 256);
            for (int i = t; i < 4096; i += 256) {
                int r = i >> 6, c4 = i & 63;
                float4 v = row[r*64 + c4];
                half4_t hv; hv[0]=(_Float16)v.x; hv[1]=(_Float16)v.y; hv[2]=(_Float16)v.z; hv[3]=(_Float16)v.w;
                *(half4_t*)&xs[(r + 3)*LDR + c4*4] = hv;
            }
        } else {
            half4_t z; z[0]=(_Float16)0.f; z[1]=(_Float16)0.f; z[2]=(_Float16)0.f; z[3]=(_Float16)0.f;
            for (int i = t; i < 4096; i += 256) {
                int r = i >> 6, c4 = i & 63;
                *(half4_t*)&xs[(r + 3)*LDR + c4*4] = z;
            }
        }
        __syncthreads();
        #pragma unroll
        for (int kj = 0; kj < 3; kj++) {
            const _Float16* wt = Wh + (size_t)(ki*3 + kj)*32*256;
            int wrow = wid*16 + l16 + (kj - 1)*DIL + 3;
            #pragma unroll
            for (int cs = 0; cs < 8; cs++) {
                int k = cs*32 + quad*8;
                half8_t a = *(const half8_t*)&xs[wrow*LDR + k];
                half8_t b0 = *(const half8_t*)&wt[(size_t)l16*256 + k];
                half8_t b1 = *(const half8_t*)&wt[(size_t)(16 + l16)*256 + k];
                acc[0] = __builtin_amdgcn_mfma_f32_16x16x32_f16(a, b0, acc[0], 0, 0, 0);
                acc[1] = __builtin_amdgcn_mfma_f32_16x16x32_f16(a, b1, acc[1], 0, 0, 0);
            }
        }
    }
    int pbase = (b*64 + h)*64;
    #pragma unroll
    for (int nf = 0; nf < 2; nf++) {
        int kcol = nf*16 + l16;
        if (kcol < 27) {
            float bs = bias[kcol];
            #pragma unroll
            for (int r = 0; r < 4; r++) {
                int w = wid*16 + quad*4 + r;
                off[(size_t)(pbase + w)*27 + kcol] = acc[nf][r] + bs;
            }
        }
    }
}

// ---------------- modulated deformable depthwise 3x3 (fp32) ----------------
template<int DIL>
__global__ void __launch_bounds__(256) deform_kernel(const float* __restrict__ src, const float* __restrict__ off,
        const float* __restrict__ dwt, const float* __restrict__ dwb, float* __restrict__ out) {
    int bh = blockIdx.x;
    int b = bh >> 6, h = bh & 63;
    int t = threadIdx.x;
    int c4 = t & 63;
    int ps = t >> 6;
    float4 dwv[9];
    #pragma unroll
    for (int kk = 0; kk < 9; kk++) dwv[kk] = ((const float4*)dwt)[kk*64 + c4];
    float4 bv = ((const float4*)dwb)[c4];
    const float4* srcf = (const float4*)src;
    for (int i = 0; i < 16; i++) {
        int w = ps*16 + i;
        int p = (b*64 + h)*64 + w;
        const float* op = off + (size_t)p*27;
        float4 acc = make_float4(0.f,0.f,0.f,0.f);
        #pragma unroll
        for (int kk = 0; kk < 9; kk++) {
            int ki = kk / 3, kj = kk % 3;
            float ox = op[kk];
            float oy = op[9 + kk];
            float mm = op[18 + kk];
            mm = 1.0f / (1.0f + expf(-mm));
            float py = (float)(h - DIL + ki*DIL) + oy;
            float px = (float)(w - DIL + kj*DIL) + ox;
            float y0f = floorf(py), x0f = floorf(px);
            float wy = py - y0f, wx = px - x0f;
            int y0 = (int)y0f, x0 = (int)x0f;
            int y1 = y0 + 1, x1 = x0 + 1;
            float w00 = (1.f - wy)*(1.f - wx), w01 = (1.f - wy)*wx;
            float w10 = wy*(1.f - wx), w11 = wy*wx;
            float4 s = make_float4(0.f,0.f,0.f,0.f);
            bool xv0 = (x0 >= 0) && (x0 < 64);
            bool xv1 = (x1 >= 0) && (x1 < 64);
            if (y0 >= 0 && y0 < 64) {
                const float4* r0 = srcf + (size_t)((b*64 + y0)*64) * 64;
                if (xv0) { float4 v = r0[x0*64 + c4]; s.x += v.x*w00; s.y += v.y*w00; s.z += v.z*w00; s.w += v.w*w00; }
                if (xv1) { float4 v = r0[x1*64 + c4]; s.x += v.x*w01; s.y += v.y*w01; s.z += v.z*w01; s.w += v.w*w01; }
            }
            if (y1 >= 0 && y1 < 64) {
                const float4* r1 = srcf + (size_t)((b*64 + y1)*64) * 64;
                if (xv0) { float4 v = r1[x0*64 + c4]; s.x += v.x*w10; s.y += v.y*w10; s.z += v.z*w10; s.w += v.w*w10; }
                if (xv1) { float4 v = r1[x1*64 + c4]; s.x += v.x*w11; s.y += v.y*w11; s.z += v.z*w11; s.w += v.w*w11; }
            }
            acc.x += s.x * mm * dwv[kk].x;
            acc.y += s.y * mm * dwv[kk].y;
            acc.z += s.z * mm * dwv[kk].z;
            acc.w += s.w * mm * dwv[kk].w;
        }
        float4 o4;
        o4.x = acc.x + bv.x; o4.y = acc.y + bv.y; o4.z = acc.z + bv.z; o4.w = acc.w + bv.w;
        ((float4*)out)[(size_t)p*64 + c4] = o4;
    }
}

// ---------------- xg = x*a + img; LayerNorm over C ----------------
__global__ void __launch_bounds__(256) gate_ln_kernel(const float* __restrict__ x, const float* __restrict__ a,
        const float* __restrict__ img, const float* __restrict__ g, const float* __restrict__ bb,
        float* __restrict__ out) {
    int t = threadIdx.x;
    int lane = t & 63;
    int wv = t >> 6;
    int p = blockIdx.x*4 + wv;
    float4 xv = ((const float4*)x)[p*64 + lane];
    float4 av = ((const float4*)a)[p*64 + lane];
    float4 iv = ((const float4*)img)[p*64 + lane];
    float4 v;
    v.x = xv.x*av.x + iv.x; v.y = xv.y*av.y + iv.y;
    v.z = xv.z*av.z + iv.z; v.w = xv.w*av.w + iv.w;
    float s = v.x + v.y + v.z + v.w;
    float s2 = v.x*v.x + v.y*v.y + v.z*v.z + v.w*v.w;
    #pragma unroll
    for (int o = 1; o < 64; o <<= 1) { s += __shfl_xor(s, o); s2 += __shfl_xor(s2, o); }
    float m = s * (1.f/256.f);
    float var = s2 * (1.f/256.f) - m*m;
    float r = rsqrtf(var + 1e-5f);
    float4 gv = ((const float4*)g)[lane];
    float4 bv = ((const float4*)bb)[lane];
    float4 o4;
    o4.x = (v.x - m)*r*gv.x + bv.x;
    o4.y = (v.y - m)*r*gv.y + bv.y;
    o4.z = (v.z - m)*r*gv.z + bv.z;
    o4.w = (v.w - m)*r*gv.w + bv.w;
    ((float4*)out)[p*64 + lane] = o4;
}

// ---------------- depthwise 3x3 pad=1 + gelu (NHWC) ----------------
__global__ void __launch_bounds__(256) dw3x3_kernel(const float* __restrict__ in, const float* __restrict__ wt,
        const float* __restrict__ bias, float* __restrict__ out) {
    int gid = blockIdx.x*256 + threadIdx.x;
    int c4 = gid & 63;
    int p = gid >> 6;
    int w = p & 63;
    int h = (p >> 6) & 63;
    int b = p >> 12;
    float4 acc = ((const float4*)bias)[c4];
    #pragma unroll
    for (int ki = 0; ki < 3; ki++) {
        int hh = h + ki - 1;
        if (hh < 0 || hh >= 64) continue;
        #pragma unroll
        for (int kj = 0; kj < 3; kj++) {
            int wwp = w + kj - 1;
            if (wwp < 0 || wwp >= 64) continue;
            float4 v = ((const float4*)in)[((b*64 + hh)*64 + wwp)*64 + c4];
            float4 wv = ((const float4*)wt)[(ki*3 + kj)*64 + c4];
            acc.x += v.x*wv.x; acc.y += v.y*wv.y; acc.z += v.z*wv.z; acc.w += v.w*wv.w;
        }
    }
    acc.x = gelu_f(acc.x); acc.y = gelu_f(acc.y); acc.z = gelu_f(acc.z); acc.w = gelu_f(acc.w);
    ((float4*)out)[p*64 + c4] = acc;
}

// ---------------- 8-token cross attention + alpha residual ----------------
__global__ void __launch_bounds__(256) attn_kernel(const float* __restrict__ dense, const float* __restrict__ tok,
        const float* __restrict__ alpha, float* __restrict__ out) {
    __shared__ float4 t_s[8*64];
    __shared__ float4 al_s[64];
    int bh = blockIdx.x;
    int b = bh >> 6, h = bh & 63;
    int t = threadIdx.x;
    for (int i = t; i < 512; i += 256) t_s[i] = ((const float4*)tok)[b*512 + i];
    if (t < 64) al_s[t] = ((const float4*)alpha)[t];
    __syncthreads();
    int lane = t & 63, ps = t >> 6;
    for (int i = 0; i < 16; i++) {
        int w = ps*16 + i;
        int p = (b*64 + h)*64 + w;
        float4 dv = ((const float4*)dense)[p*64 + lane];
        float sc[8];
        #pragma unroll
        for (int q = 0; q < 8; q++) {
            float4 tv = t_s[q*64 + lane];
            float partial = dv.x*tv.x + dv.y*tv.y + dv.z*tv.z + dv.w*tv.w;
            #pragma unroll
            for (int o = 1; o < 64; o <<= 1) partial += __shfl_xor(partial, o);
            sc[q] = partial * 0.0625f;   // scale = 256^-0.5
        }
        float mx = sc[0];
        #pragma unroll
        for (int q = 1; q < 8; q++) mx = fmaxf(mx, sc[q]);
        float e[8]; float denom = 0.f;
        #pragma unroll
        for (int q = 0; q < 8; q++) { e[q] = expf(sc[q] - mx); denom += e[q]; }
        float inv = 1.0f / denom;
        float4 al = al_s[lane];
        float4 o4;
        o4.x = dv.x*al.x; o4.y = dv.y*al.y; o4.z = dv.z*al.z; o4.w = dv.w*al.w;
        #pragma unroll
        for (int q = 0; q < 8; q++) {
            float wq = e[q]*inv;
            float4 tv = t_s[q*64 + lane];
            o4.x += wq*tv.x; o4.y += wq*tv.y; o4.z += wq*tv.z; o4.w += wq*tv.w;
        }
        ((float4*)out)[p*64 + lane] = o4;
    }
}

// ---------------- NHWC -> NCHW ----------------
__global__ void nhwc_to_nchw_kernel(const float* __restrict__ in, float* __restrict__ out) {
    int b = blockIdx.z;
    int c0 = blockIdx.y*32, s0 = blockIdx.x*32;
    __shared__ float tile[32][33];
    int tx = threadIdx.x, ty = threadIdx.y;
    #pragma unroll
    for (int r = 0; r < 4; r++) {
        int sl = ty + 8*r;
        tile[tx][sl] = in[(b*HWs + s0 + sl)*CC + c0 + tx];
    }
    __syncthreads();
    #pragma unroll
    for (int r = 0; r < 4; r++) {
        int cl = ty + 8*r;
        out[(b*CC + c0 + cl)*HWs + s0 + tx] = tile[cl][tx];
    }
}

extern "C" void kernel_launch(void* const* d_in, const int* in_sizes, int n_in,
                              void* d_out, int out_size, void* d_ws, size_t ws_size,
                              hipStream_t stream) {
    const float* image_embed = (const float*)d_in[0];
    const float* inter_p     = (const float*)d_in[1];
    const float* intra_p     = (const float*)d_in[2];
    const float* masks       = (const float*)d_in[3];
    const float* proj_w      = (const float*)d_in[4];
    const float* proj_b      = (const float*)d_in[5];
    const float* lin_w       = (const float*)d_in[6];
    const float* lin_b       = (const float*)d_in[7];
    const float* tok_g       = (const float*)d_in[8];
    const float* tok_b       = (const float*)d_in[9];
    const float* alpha       = (const float*)d_in[10];
    const float* in_w        = (const float*)d_in[11];
    const float* in_b        = (const float*)d_in[12];
    const float* off0_w      = (const float*)d_in[13];
    const float* off0_b      = (const float*)d_in[14];
    const float* dw0_w       = (const float*)d_in[15];
    const float* dw0_b       = (const float*)d_in[16];
    const float* off1_w      = (const float*)d_in[17];
    const float* off1_b      = (const float*)d_in[18];
    const float* dw1_w       = (const float*)d_in[19];
    const float* dw1_b       = (const float*)d_in[20];
    const float* cv_w        = (const float*)d_in[21];
    const float* cv_b        = (const float*)d_in[22];
    const float* ln_g        = (const float*)d_in[23];
    const float* ln_b        = (const float*)d_in[24];
    const float* op0_w       = (const float*)d_in[25];
    const float* op0_b       = (const float*)d_in[26];
    const float* op1_w       = (const float*)d_in[27];
    const float* op1_b       = (const float*)d_in[28];
    const float* op2_w       = (const float*)d_in[29];
    const float* op2_b       = (const float*)d_in[30];
    const float* out0_w      = (const float*)d_in[31];
    const float* out0_b      = (const float*)d_in[32];
    const float* out1_w      = (const float*)d_in[33];
    const float* out1_b      = (const float*)d_in[34];
    (void)ws_size; (void)in_sizes; (void)n_in; (void)out_size;

    float* ws = (float*)d_ws;
    const size_t BIG = (size_t)PP * CC;     // 16,777,216 floats (64 MiB)
    float* A   = ws;                        // img -> xln -> o(NHWC)
    float* Bb  = A + BIG;                   // x -> y0 -> attn
    float* Cb  = Bb + BIG;                  // a1 -> a -> y1 -> o0
    float* D   = (float*)d_out;             // a2 -> dense -> final NCHW out
    float* OFF = Cb + BIG;                  // [P][27]
    float* TOK = OFF + (size_t)PP*27;       // [16][8][256]
    float* DWT0 = TOK + BB*QQ*CC;
    float* DWT1 = DWT0 + 9*256;
    float* OP1T = DWT1 + 9*256;
    _Float16* WH_IN   = (_Float16*)(OP1T + 9*256);
    _Float16* WH_CV   = WH_IN + 65536;
    _Float16* WH_OP0  = WH_CV + 65536;
    _Float16* WH_OP2  = WH_OP0 + 65536;
    _Float16* WH_OUT0 = WH_OP2 + 65536;
    _Float16* WH_OUT1 = WH_OUT0 + 32768;
    _Float16* WHOFF0  = WH_OUT1 + 32768;
    _Float16* WHOFF1  = WHOFF0 + 9*32*256;
    // ws total ~= 200 MiB

    prep_weights_kernel<<<(9*32*256 + 255)/256, 256, 0, stream>>>(
        off0_w, off1_w, dw0_w, dw1_w, op1_w,
        in_w, cv_w, op0_w, op2_w, out0_w, out1_w,
        DWT0, DWT1, OP1T,
        WH_IN, WH_CV, WH_OP0, WH_OP2, WH_OUT0, WH_OUT1, WHOFF0, WHOFF1);
    token_kernel<<<BB*QQ, 256, 0, stream>>>(inter_p, intra_p, proj_w, proj_b,
                                            lin_w, lin_b, tok_g, tok_b, TOK);
    // img = ie*(1+pe) -> NHWC
    img_pe_kernel<<<dim3(HWs/32, CC/32, BB), dim3(32,8), 0, stream>>>(image_embed, intra_p, masks, A);
    // x = gelu(conv1x1(img))
    conv1x1_mfma<256,256,1,false><<<PP/64, 256, 0, stream>>>(A, WH_IN, in_b, nullptr, Bb);
    // deform block 1 (dil=1)
    off_conv_mfma<1><<<BB*HH, 256, 0, stream>>>(Bb, WHOFF0, off0_b, OFF);
    deform_kernel<1><<<BB*HH, 256, 0, stream>>>(Bb, OFF, DWT0, dw0_b, Cb);
    // deform block 2 (dil=3)
    off_conv_mfma<3><<<BB*HH, 256, 0, stream>>>(Cb, WHOFF1, off1_b, OFF);
    deform_kernel<3><<<BB*HH, 256, 0, stream>>>(Cb, OFF, DWT1, dw1_b, D);
    // a = conv1x1(a2)
    conv1x1_mfma<256,256,0,false><<<PP/64, 256, 0, stream>>>(D, WH_CV, cv_b, nullptr, Cb);
    // x = LN2d(x*a + img)
    gate_ln_kernel<<<PP/4, 256, 0, stream>>>(Bb, Cb, A, ln_g, ln_b, A);
    // y = conv1x1(x)
    conv1x1_mfma<256,256,0,false><<<PP/64, 256, 0, stream>>>(A, WH_OP0, op0_b, nullptr, Bb);
    // y = gelu(dw3x3(y))
    dw3x3_kernel<<<PP*64/256, 256, 0, stream>>>(Bb, OP1T, op1_b, Cb);
    // dense = conv1x1(y) + x
    conv1x1_mfma<256,256,0,true><<<PP/64, 256, 0, stream>>>(Cb, WH_OP2, op2_b, A, D);
    // attn = softmax-xattn(dense, t) + dense*alpha
    attn_kernel<<<BB*HH, 256, 0, stream>>>(D, TOK, alpha, Bb);
    // o = gelu(conv1x1_128(attn))
    conv1x1_mfma<256,128,1,false><<<PP/64, 256, 0, stream>>>(Bb, WH_OUT0, out0_b, nullptr, Cb);
    // o = conv1x1(o) -> NHWC into A
    conv1x1_mfma<128,256,0,false><<<PP/64, 256, 0, stream>>>(Cb, WH_OUT1, out1_b, nullptr, A);
    // NHWC -> NCHW final output
    nhwc_to_nchw_kernel<<<dim3(HWs/32, CC/32, BB), dim3(32,8), 0, stream>>>(A, (float*)d_out);
}

// Round 5
// 1268.326 us; speedup vs baseline: 3.1377x; 1.0928x over previous
//
#include <hip/hip_runtime.h>
#include <math.h>

#define BB 16
#define CC 256
#define HH 64
#define WW 64
#define HWs 4096
#define PP 65536   // BB*HWs
#define QQ 8
#define NN 9

typedef _Float16 half8_t __attribute__((ext_vector_type(8)));
typedef _Float16 half4_t __attribute__((ext_vector_type(4)));
typedef float floatx4 __attribute__((ext_vector_type(4)));

__device__ __forceinline__ float gelu_f(float x) {
    return 0.5f * x * (1.0f + erff(x * 0.70710678118654752f));
}

// ---------------- weight prep ----------------
__global__ void prep_weights_kernel(const float* __restrict__ off0_w, const float* __restrict__ off1_w,
                                    const float* __restrict__ dw0_w, const float* __restrict__ dw1_w,
                                    const float* __restrict__ op1_w,
                                    const float* __restrict__ in_w, const float* __restrict__ cv_w,
                                    const float* __restrict__ op0_w, const float* __restrict__ op2_w,
                                    const float* __restrict__ out0_w, const float* __restrict__ out1_w,
                                    float* __restrict__ dwt0, float* __restrict__ dwt1,
                                    float* __restrict__ op1t,
                                    _Float16* __restrict__ wh_in, _Float16* __restrict__ wh_cv,
                                    _Float16* __restrict__ wh_op0, _Float16* __restrict__ wh_op2,
                                    _Float16* __restrict__ wh_out0, _Float16* __restrict__ wh_out1,
                                    _Float16* __restrict__ whoff0, _Float16* __restrict__ whoff1) {
    int i = blockIdx.x * 256 + threadIdx.x;
    if (i < 9*256) {
        int c = i & 255;
        int tap = i >> 8;
        dwt0[i] = dw0_w[c*9 + tap];
        dwt1[i] = dw1_w[c*9 + tap];
        op1t[i] = op1_w[c*9 + tap];
    }
    if (i < 65536) {            // [256][256] f16 direct casts
        wh_in[i]  = (_Float16)in_w[i];
        wh_cv[i]  = (_Float16)cv_w[i];
        wh_op0[i] = (_Float16)op0_w[i];
        wh_op2[i] = (_Float16)op2_w[i];
    }
    if (i < 32768) {            // out0: [128][256], out1: [256][128]
        wh_out0[i] = (_Float16)out0_w[i];
        wh_out1[i] = (_Float16)out1_w[i];
    }
    if (i < 9*32*256) {         // whoff[tap][k32][ci], zero-padded k>=27
        int ci = i & 255;
        int k32 = (i >> 8) & 31;
        int tap = i >> 13;
        float v0 = 0.f, v1 = 0.f;
        if (k32 < 27) {
            v0 = off0_w[(k32*256 + ci)*9 + tap];
            v1 = off1_w[(k32*256 + ci)*9 + tap];
        }
        whoff0[i] = (_Float16)v0;
        whoff1[i] = (_Float16)v1;
    }
}

// ---------------- token path ----------------
__global__ void token_kernel(const float* __restrict__ inter, const float* __restrict__ intra,
                             const float* __restrict__ proj_w, const float* __restrict__ proj_b,
                             const float* __restrict__ lin_w, const float* __restrict__ lin_b,
                             const float* __restrict__ tok_g, const float* __restrict__ tok_b,
                             float* __restrict__ t_out) {
    int bq = blockIdx.x;
    int b = bq >> 3, q = bq & 7;
    int c = threadIdx.x;
    __shared__ float inter_s[256];
    __shared__ float pt_s[9];
    __shared__ float g_s[256];
    __shared__ float red[256];
    __shared__ float stat[2];
    inter_s[c] = inter[(b*QQ + q)*CC + c];
    __syncthreads();
    for (int n = 0; n < 9; n++) {
        red[c] = inter_s[c] * intra[(b*NN + n)*CC + c];
        __syncthreads();
        for (int s = 128; s > 0; s >>= 1) {
            if (c < s) red[c] += red[c + s];
            __syncthreads();
        }
        if (c == 0) pt_s[n] = red[0];
        __syncthreads();
    }
    float u = proj_b[c];
    for (int k = 0; k < 256; k++) u += inter_s[k] * proj_w[k*CC + c];
    for (int n = 0; n < 9; n++) u += pt_s[n] * proj_w[(256 + n)*CC + c];
    g_s[c] = gelu_f(u);
    __syncthreads();
    float v = lin_b[c];
    for (int k = 0; k < 256; k++) v += g_s[k] * lin_w[k*CC + c];
    red[c] = v;
    __syncthreads();
    for (int s = 128; s > 0; s >>= 1) { if (c < s) red[c] += red[c + s]; __syncthreads(); }
    if (c == 0) stat[0] = red[0] * (1.0f/256.0f);
    __syncthreads();
    float m = stat[0];
    red[c] = (v - m)*(v - m);
    __syncthreads();
    for (int s = 128; s > 0; s >>= 1) { if (c < s) red[c] += red[c + s]; __syncthreads(); }
    if (c == 0) stat[1] = red[0] * (1.0f/256.0f);
    __syncthreads();
    float var = stat[1];
    float r = rsqrtf(var + 1e-5f);
    t_out[(b*QQ + q)*CC + c] = (v - m) * r * tok_g[c] + tok_b[c];
}

// ---------------- img = ie*(1+pe), NCHW -> NHWC transpose ----------------
__global__ void img_pe_kernel(const float* __restrict__ ie, const float* __restrict__ intra,
                              const float* __restrict__ masks, float* __restrict__ img) {
    int b = blockIdx.z;
    int c0 = blockIdx.y * 32;
    int s0 = blockIdx.x * 32;
    __shared__ float tile[32][33];
    __shared__ float intra_s[9][32];
    __shared__ float mask_s[9][32];
    int tx = threadIdx.x, ty = threadIdx.y;
    int t = ty*32 + tx;
    for (int i = t; i < 288; i += 256) {
        int n = i >> 5, j = i & 31;
        intra_s[n][j] = intra[(b*NN + n)*CC + c0 + j];
        mask_s[n][j]  = masks[(b*NN + n)*HWs + s0 + j];
    }
    __syncthreads();
    #pragma unroll
    for (int r = 0; r < 4; r++) {
        int cl = ty + 8*r;
        float val = ie[(b*CC + c0 + cl)*HWs + s0 + tx];
        float pe = 0.f;
        #pragma unroll
        for (int n = 0; n < 9; n++) pe += intra_s[n][cl] * mask_s[n][tx];
        tile[cl][tx] = val * (1.0f + pe);
    }
    __syncthreads();
    #pragma unroll
    for (int r = 0; r < 4; r++) {
        int sl = ty + 8*r;
        img[(b*HWs + s0 + sl)*CC + c0 + tx] = tile[tx][sl];
    }
}

// ---------------- MFMA 1x1 conv (GEMM) ----------------
// INH: input buffer is f16 [p][CI]; else fp32.
// XH: additionally write f16 copy of the (activated) output.
template<int CI, int CO, int ACT, bool RES, bool INH, bool XH>
__global__ void __launch_bounds__(256) conv1x1_mfma(const void* __restrict__ in, const _Float16* __restrict__ Wh,
        const float* __restrict__ bias, const float* __restrict__ res, float* __restrict__ out,
        _Float16* __restrict__ outh) {
    constexpr int KS = CI/32;        // k-steps
    constexpr int NF = CO/64;        // n-frags per wave
    constexpr int LDR = CI + 8;      // halves per LDS row (+16B pad)
    __shared__ __align__(16) _Float16 a_lds[64*LDR];
    int t = threadIdx.x;
    int wid = t >> 6, lane = t & 63;
    int quad = lane >> 4, l16 = lane & 15;
    int p0 = blockIdx.x * 64;
    if (INH) {
        const half8_t* inh = (const half8_t*)in + (size_t)p0*(CI/8);
        for (int i = t; i < 64*(CI/8); i += 256) {
            int r = i/(CI/8), c8 = i%(CI/8);
            *(half8_t*)&a_lds[r*LDR + c8*8] = inh[i];
        }
    } else {
        const float4* inf = (const float4*)in + (size_t)p0*(CI/4);
        for (int i = t; i < 64*(CI/4); i += 256) {
            float4 v = inf[i];
            half4_t hv; hv[0]=(_Float16)v.x; hv[1]=(_Float16)v.y; hv[2]=(_Float16)v.z; hv[3]=(_Float16)v.w;
            int r = i/(CI/4), c4 = i%(CI/4);
            *(half4_t*)&a_lds[r*LDR + c4*4] = hv;
        }
    }
    __syncthreads();
    int n0 = wid*(CO/4);
    floatx4 acc[4][NF];
    #pragma unroll
    for (int mf = 0; mf < 4; mf++)
        #pragma unroll
        for (int nf = 0; nf < NF; nf++)
            #pragma unroll
            for (int r = 0; r < 4; r++) acc[mf][nf][r] = 0.f;
    for (int ks = 0; ks < KS; ks++) {
        int k = ks*32 + quad*8;
        half8_t a[4];
        #pragma unroll
        for (int mf = 0; mf < 4; mf++)
            a[mf] = *(const half8_t*)&a_lds[(mf*16 + l16)*LDR + k];
        half8_t bfr[NF];
        #pragma unroll
        for (int nf = 0; nf < NF; nf++)
            bfr[nf] = *(const half8_t*)&Wh[(size_t)(n0 + nf*16 + l16)*CI + k];
        #pragma unroll
        for (int mf = 0; mf < 4; mf++)
            #pragma unroll
            for (int nf = 0; nf < NF; nf++)
                acc[mf][nf] = __builtin_amdgcn_mfma_f32_16x16x32_f16(a[mf], bfr[nf], acc[mf][nf], 0, 0, 0);
    }
    // epilogue: C/D col=lane&15 (co), row=quad*4+reg (p)
    #pragma unroll
    for (int nf = 0; nf < NF; nf++) {
        int co = n0 + nf*16 + l16;
        float bs = bias[co];
        #pragma unroll
        for (int mf = 0; mf < 4; mf++) {
            #pragma unroll
            for (int r = 0; r < 4; r++) {
                int p = p0 + mf*16 + quad*4 + r;
                float v = acc[mf][nf][r] + bs;
                if (ACT) v = gelu_f(v);
                if (RES) v += res[(size_t)p*CO + co];
                out[(size_t)p*CO + co] = v;
                if (XH) outh[(size_t)p*CO + co] = (_Float16)v;
            }
        }
    }
}

// ---------------- MFMA 3x3 offset conv (f16 input) -> [p][27] ----------------
template<int DIL>
__global__ void __launch_bounds__(256) off_conv_mfma(const _Float16* __restrict__ x, const _Float16* __restrict__ Wh,
        const float* __restrict__ bias, float* __restrict__ off) {
    constexpr int LDR = 264;    // 256 + 16B pad, halves
    __shared__ __align__(16) _Float16 xs[70*LDR];   // w = -3..66 at idx w+3
    int bh = blockIdx.x;
    int b = bh >> 6, h = bh & 63;
    int t = threadIdx.x;
    int wid = t >> 6, lane = t & 63;
    int quad = lane >> 4, l16 = lane & 15;
    // zero the 6 margin rows once
    for (int i = t; i < 6*LDR; i += 256) {
        int r = i/LDR, c = i%LDR;
        int row = (r < 3) ? r : (64 + r);   // 0,1,2, 67,68,69
        xs[row*LDR + c] = (_Float16)0.f;
    }
    floatx4 acc[2];
    #pragma unroll
    for (int nf = 0; nf < 2; nf++)
        #pragma unroll
        for (int r = 0; r < 4; r++) acc[nf][r] = 0.f;
    for (int ki = 0; ki < 3; ki++) {
        int hrow = h + (ki - 1)*DIL;
        __syncthreads();
        if (hrow >= 0 && hrow < 64) {
            const half8_t* row = (const half8_t*)(x + ((size_t)(b*64 + hrow)*64) * 256);
            for (int i = t; i < 2048; i += 256) {
                int r = i >> 5, c8 = i & 31;
                *(half8_t*)&xs[(r + 3)*LDR + c8*8] = row[r*32 + c8];
            }
        } else {
            half8_t z = (half8_t)((_Float16)0.f);
            for (int i = t; i < 2048; i += 256) {
                int r = i >> 5, c8 = i & 31;
                *(half8_t*)&xs[(r + 3)*LDR + c8*8] = z;
            }
        }
        __syncthreads();
        #pragma unroll
        for (int kj = 0; kj < 3; kj++) {
            const _Float16* wt = Wh + (size_t)(ki*3 + kj)*32*256;
            int wrow = wid*16 + l16 + (kj - 1)*DIL + 3;
            #pragma unroll
            for (int cs = 0; cs < 8; cs++) {
                int k = cs*32 + quad*8;
                half8_t a = *(const half8_t*)&xs[wrow*LDR + k];
                half8_t b0 = *(const half8_t*)&wt[(size_t)l16*256 + k];
                half8_t b1 = *(const half8_t*)&wt[(size_t)(16 + l16)*256 + k];
                acc[0] = __builtin_amdgcn_mfma_f32_16x16x32_f16(a, b0, acc[0], 0, 0, 0);
                acc[1] = __builtin_amdgcn_mfma_f32_16x16x32_f16(a, b1, acc[1], 0, 0, 0);
            }
        }
    }
    int pbase = (b*64 + h)*64;
    #pragma unroll
    for (int nf = 0; nf < 2; nf++) {
        int kcol = nf*16 + l16;
        if (kcol < 27) {
            float bs = bias[kcol];
            #pragma unroll
            for (int r = 0; r < 4; r++) {
                int w = wid*16 + quad*4 + r;
                off[(size_t)(pbase + w)*27 + kcol] = acc[nf][r] + bs;
            }
        }
    }
}

// ---------------- modulated deformable depthwise 3x3 (f16 src/out, fp32 math) ----------------
template<int DIL>
__global__ void __launch_bounds__(256) deform_kernel(const _Float16* __restrict__ src, const float* __restrict__ off,
        const float* __restrict__ dwt, const float* __restrict__ dwb, _Float16* __restrict__ out) {
    int bh = blockIdx.x;
    int b = bh >> 6, h = bh & 63;
    int t = threadIdx.x;
    int c4 = t & 63;
    int ps = t >> 6;
    float4 dwv[9];
    #pragma unroll
    for (int kk = 0; kk < 9; kk++) dwv[kk] = ((const float4*)dwt)[kk*64 + c4];
    float4 bv = ((const float4*)dwb)[c4];
    const half4_t* srcf = (const half4_t*)src;
    for (int i = 0; i < 16; i++) {
        int w = ps*16 + i;
        int p = (b*64 + h)*64 + w;
        const float* op = off + (size_t)p*27;
        float4 acc = make_float4(0.f,0.f,0.f,0.f);
        #pragma unroll
        for (int kk = 0; kk < 9; kk++) {
            int ki = kk / 3, kj = kk % 3;
            float ox = op[kk];
            float oy = op[9 + kk];
            float mm = op[18 + kk];
            mm = 1.0f / (1.0f + expf(-mm));
            float py = (float)(h - DIL + ki*DIL) + oy;
            float px = (float)(w - DIL + kj*DIL) + ox;
            float y0f = floorf(py), x0f = floorf(px);
            float wy = py - y0f, wx = px - x0f;
            int y0 = (int)y0f, x0 = (int)x0f;
            int y1 = y0 + 1, x1 = x0 + 1;
            float w00 = (1.f - wy)*(1.f - wx), w01 = (1.f - wy)*wx;
            float w10 = wy*(1.f - wx), w11 = wy*wx;
            float4 s = make_float4(0.f,0.f,0.f,0.f);
            bool xv0 = (x0 >= 0) && (x0 < 64);
            bool xv1 = (x1 >= 0) && (x1 < 64);
            if (y0 >= 0 && y0 < 64) {
                const half4_t* r0 = srcf + (size_t)((b*64 + y0)*64) * 64;
                if (xv0) { half4_t v = r0[x0*64 + c4]; s.x += (float)v[0]*w00; s.y += (float)v[1]*w00; s.z += (float)v[2]*w00; s.w += (float)v[3]*w00; }
                if (xv1) { half4_t v = r0[x1*64 + c4]; s.x += (float)v[0]*w01; s.y += (float)v[1]*w01; s.z += (float)v[2]*w01; s.w += (float)v[3]*w01; }
            }
            if (y1 >= 0 && y1 < 64) {
                const half4_t* r1 = srcf + (size_t)((b*64 + y1)*64) * 64;
                if (xv0) { half4_t v = r1[x0*64 + c4]; s.x += (float)v[0]*w10; s.y += (float)v[1]*w10; s.z += (float)v[2]*w10; s.w += (float)v[3]*w10; }
                if (xv1) { half4_t v = r1[x1*64 + c4]; s.x += (float)v[0]*w11; s.y += (float)v[1]*w11; s.z += (float)v[2]*w11; s.w += (float)v[3]*w11; }
            }
            acc.x += s.x * mm * dwv[kk].x;
            acc.y += s.y * mm * dwv[kk].y;
            acc.z += s.z * mm * dwv[kk].z;
            acc.w += s.w * mm * dwv[kk].w;
        }
        half4_t o4;
        o4[0] = (_Float16)(acc.x + bv.x);
        o4[1] = (_Float16)(acc.y + bv.y);
        o4[2] = (_Float16)(acc.z + bv.z);
        o4[3] = (_Float16)(acc.w + bv.w);
        ((half4_t*)out)[(size_t)p*64 + c4] = o4;
    }
}

// ---------------- xg = x*a + img; LayerNorm over C ----------------
__global__ void __launch_bounds__(256) gate_ln_kernel(const float* __restrict__ x, const float* __restrict__ a,
        const float* __restrict__ img, const float* __restrict__ g, const float* __restrict__ bb,
        float* __restrict__ out) {
    int t = threadIdx.x;
    int lane = t & 63;
    int wv = t >> 6;
    int p = blockIdx.x*4 + wv;
    float4 xv = ((const float4*)x)[p*64 + lane];
    float4 av = ((const float4*)a)[p*64 + lane];
    float4 iv = ((const float4*)img)[p*64 + lane];
    float4 v;
    v.x = xv.x*av.x + iv.x; v.y = xv.y*av.y + iv.y;
    v.z = xv.z*av.z + iv.z; v.w = xv.w*av.w + iv.w;
    float s = v.x + v.y + v.z + v.w;
    float s2 = v.x*v.x + v.y*v.y + v.z*v.z + v.w*v.w;
    #pragma unroll
    for (int o = 1; o < 64; o <<= 1) { s += __shfl_xor(s, o); s2 += __shfl_xor(s2, o); }
    float m = s * (1.f/256.f);
    float var = s2 * (1.f/256.f) - m*m;
    float r = rsqrtf(var + 1e-5f);
    float4 gv = ((const float4*)g)[lane];
    float4 bv = ((const float4*)bb)[lane];
    float4 o4;
    o4.x = (v.x - m)*r*gv.x + bv.x;
    o4.y = (v.y - m)*r*gv.y + bv.y;
    o4.z = (v.z - m)*r*gv.z + bv.z;
    o4.w = (v.w - m)*r*gv.w + bv.w;
    ((float4*)out)[p*64 + lane] = o4;
}

// ---------------- depthwise 3x3 pad=1 + gelu (NHWC) ----------------
__global__ void __launch_bounds__(256) dw3x3_kernel(const float* __restrict__ in, const float* __restrict__ wt,
        const float* __restrict__ bias, float* __restrict__ out) {
    int gid = blockIdx.x*256 + threadIdx.x;
    int c4 = gid & 63;
    int p = gid >> 6;
    int w = p & 63;
    int h = (p >> 6) & 63;
    int b = p >> 12;
    float4 acc = ((const float4*)bias)[c4];
    #pragma unroll
    for (int ki = 0; ki < 3; ki++) {
        int hh = h + ki - 1;
        if (hh < 0 || hh >= 64) continue;
        #pragma unroll
        for (int kj = 0; kj < 3; kj++) {
            int wwp = w + kj - 1;
            if (wwp < 0 || wwp >= 64) continue;
            float4 v = ((const float4*)in)[((b*64 + hh)*64 + wwp)*64 + c4];
            float4 wv = ((const float4*)wt)[(ki*3 + kj)*64 + c4];
            acc.x += v.x*wv.x; acc.y += v.y*wv.y; acc.z += v.z*wv.z; acc.w += v.w*wv.w;
        }
    }
    acc.x = gelu_f(acc.x); acc.y = gelu_f(acc.y); acc.z = gelu_f(acc.z); acc.w = gelu_f(acc.w);
    ((float4*)out)[p*64 + c4] = acc;
}

// ---------------- 8-token cross attention + alpha residual ----------------
__global__ void __launch_bounds__(256) attn_kernel(const float* __restrict__ dense, const float* __restrict__ tok,
        const float* __restrict__ alpha, float* __restrict__ out) {
    __shared__ float4 t_s[8*64];
    __shared__ float4 al_s[64];
    int bh = blockIdx.x;
    int b = bh >> 6, h = bh & 63;
    int t = threadIdx.x;
    for (int i = t; i < 512; i += 256) t_s[i] = ((const float4*)tok)[b*512 + i];
    if (t < 64) al_s[t] = ((const float4*)alpha)[t];
    __syncthreads();
    int lane = t & 63, ps = t >> 6;
    for (int i = 0; i < 16; i++) {
        int w = ps*16 + i;
        int p = (b*64 + h)*64 + w;
        float4 dv = ((const float4*)dense)[p*64 + lane];
        float sc[8];
        #pragma unroll
        for (int q = 0; q < 8; q++) {
            float4 tv = t_s[q*64 + lane];
            float partial = dv.x*tv.x + dv.y*tv.y + dv.z*tv.z + dv.w*tv.w;
            #pragma unroll
            for (int o = 1; o < 64; o <<= 1) partial += __shfl_xor(partial, o);
            sc[q] = partial * 0.0625f;   // scale = 256^-0.5
        }
        float mx = sc[0];
        #pragma unroll
        for (int q = 1; q < 8; q++) mx = fmaxf(mx, sc[q]);
        float e[8]; float denom = 0.f;
        #pragma unroll
        for (int q = 0; q < 8; q++) { e[q] = expf(sc[q] - mx); denom += e[q]; }
        float inv = 1.0f / denom;
        float4 al = al_s[lane];
        float4 o4;
        o4.x = dv.x*al.x; o4.y = dv.y*al.y; o4.z = dv.z*al.z; o4.w = dv.w*al.w;
        #pragma unroll
        for (int q = 0; q < 8; q++) {
            float wq = e[q]*inv;
            float4 tv = t_s[q*64 + lane];
            o4.x += wq*tv.x; o4.y += wq*tv.y; o4.z += wq*tv.z; o4.w += wq*tv.w;
        }
        ((float4*)out)[p*64 + lane] = o4;
    }
}

// ---------------- NHWC -> NCHW ----------------
__global__ void nhwc_to_nchw_kernel(const float* __restrict__ in, float* __restrict__ out) {
    int b = blockIdx.z;
    int c0 = blockIdx.y*32, s0 = blockIdx.x*32;
    __shared__ float tile[32][33];
    int tx = threadIdx.x, ty = threadIdx.y;
    #pragma unroll
    for (int r = 0; r < 4; r++) {
        int sl = ty + 8*r;
        tile[tx][sl] = in[(b*HWs + s0 + sl)*CC + c0 + tx];
    }
    __syncthreads();
    #pragma unroll
    for (int r = 0; r < 4; r++) {
        int cl = ty + 8*r;
        out[(b*CC + c0 + cl)*HWs + s0 + tx] = tile[cl][tx];
    }
}

extern "C" void kernel_launch(void* const* d_in, const int* in_sizes, int n_in,
                              void* d_out, int out_size, void* d_ws, size_t ws_size,
                              hipStream_t stream) {
    const float* image_embed = (const float*)d_in[0];
    const float* inter_p     = (const float*)d_in[1];
    const float* intra_p     = (const float*)d_in[2];
    const float* masks       = (const float*)d_in[3];
    const float* proj_w      = (const float*)d_in[4];
    const float* proj_b      = (const float*)d_in[5];
    const float* lin_w       = (const float*)d_in[6];
    const float* lin_b       = (const float*)d_in[7];
    const float* tok_g       = (const float*)d_in[8];
    const float* tok_b       = (const float*)d_in[9];
    const float* alpha       = (const float*)d_in[10];
    const float* in_w        = (const float*)d_in[11];
    const float* in_b        = (const float*)d_in[12];
    const float* off0_w      = (const float*)d_in[13];
    const float* off0_b      = (const float*)d_in[14];
    const float* dw0_w       = (const float*)d_in[15];
    const float* dw0_b       = (const float*)d_in[16];
    const float* off1_w      = (const float*)d_in[17];
    const float* off1_b      = (const float*)d_in[18];
    const float* dw1_w       = (const float*)d_in[19];
    const float* dw1_b       = (const float*)d_in[20];
    const float* cv_w        = (const float*)d_in[21];
    const float* cv_b        = (const float*)d_in[22];
    const float* ln_g        = (const float*)d_in[23];
    const float* ln_b        = (const float*)d_in[24];
    const float* op0_w       = (const float*)d_in[25];
    const float* op0_b       = (const float*)d_in[26];
    const float* op1_w       = (const float*)d_in[27];
    const float* op1_b       = (const float*)d_in[28];
    const float* op2_w       = (const float*)d_in[29];
    const float* op2_b       = (const float*)d_in[30];
    const float* out0_w      = (const float*)d_in[31];
    const float* out0_b      = (const float*)d_in[32];
    const float* out1_w      = (const float*)d_in[33];
    const float* out1_b      = (const float*)d_in[34];
    (void)ws_size; (void)in_sizes; (void)n_in; (void)out_size;

    float* ws = (float*)d_ws;
    const size_t BIG = (size_t)PP * CC;     // 16,777,216 floats (64 MiB)
    float* A   = ws;                        // img -> xln -> o(NHWC)
    float* Bb  = A + BIG;                   // x (fp32) -> y0 -> attn
    float* Cb  = Bb + BIG;                  // [alias: a1h f16 in first half] -> a -> y1 -> o0
    float* D   = (float*)d_out;             // [alias: xh/a2h f16 in first half] -> dense -> final out
    float* OFF = Cb + BIG;                  // [P][27]
    float* TOK = OFF + (size_t)PP*27;       // [16][8][256]
    float* DWT0 = TOK + BB*QQ*CC;
    float* DWT1 = DWT0 + 9*256;
    float* OP1T = DWT1 + 9*256;
    _Float16* WH_IN   = (_Float16*)(OP1T + 9*256);
    _Float16* WH_CV   = WH_IN + 65536;
    _Float16* WH_OP0  = WH_CV + 65536;
    _Float16* WH_OP2  = WH_OP0 + 65536;
    _Float16* WH_OUT0 = WH_OP2 + 65536;
    _Float16* WH_OUT1 = WH_OUT0 + 32768;
    _Float16* WHOFF0  = WH_OUT1 + 32768;
    _Float16* WHOFF1  = WHOFF0 + 9*32*256;
    // f16 aliases (each 32 MiB): XH in d_out (dead before dense written),
    // A1H in Cb (dead before cv output written), A2H reuses XH region.
    _Float16* XH  = (_Float16*)d_out;
    _Float16* A1H = (_Float16*)Cb;
    _Float16* A2H = XH;
    // ws total ~= 209.5 MiB

    prep_weights_kernel<<<(9*32*256 + 255)/256, 256, 0, stream>>>(
        off0_w, off1_w, dw0_w, dw1_w, op1_w,
        in_w, cv_w, op0_w, op2_w, out0_w, out1_w,
        DWT0, DWT1, OP1T,
        WH_IN, WH_CV, WH_OP0, WH_OP2, WH_OUT0, WH_OUT1, WHOFF0, WHOFF1);
    token_kernel<<<BB*QQ, 256, 0, stream>>>(inter_p, intra_p, proj_w, proj_b,
                                            lin_w, lin_b, tok_g, tok_b, TOK);
    // img = ie*(1+pe) -> NHWC
    img_pe_kernel<<<dim3(HWs/32, CC/32, BB), dim3(32,8), 0, stream>>>(image_embed, intra_p, masks, A);
    // x = gelu(conv1x1(img)), fp32 + f16 copy
    conv1x1_mfma<256,256,1,false,false,true><<<PP/64, 256, 0, stream>>>(A, WH_IN, in_b, nullptr, Bb, XH);
    // deform block 1 (dil=1), f16 path
    off_conv_mfma<1><<<BB*HH, 256, 0, stream>>>(XH, WHOFF0, off0_b, OFF);
    deform_kernel<1><<<BB*HH, 256, 0, stream>>>(XH, OFF, DWT0, dw0_b, A1H);
    // deform block 2 (dil=3)
    off_conv_mfma<3><<<BB*HH, 256, 0, stream>>>(A1H, WHOFF1, off1_b, OFF);
    deform_kernel<3><<<BB*HH, 256, 0, stream>>>(A1H, OFF, DWT1, dw1_b, A2H);
    // a = conv1x1(a2) (f16 in, fp32 out into Cb — a1h alias dead now)
    conv1x1_mfma<256,256,0,false,true,false><<<PP/64, 256, 0, stream>>>(A2H, WH_CV, cv_b, nullptr, Cb, nullptr);
    // x = LN2d(x*a + img)
    gate_ln_kernel<<<PP/4, 256, 0, stream>>>(Bb, Cb, A, ln_g, ln_b, A);
    // y = conv1x1(x)
    conv1x1_mfma<256,256,0,false,false,false><<<PP/64, 256, 0, stream>>>(A, WH_OP0, op0_b, nullptr, Bb, nullptr);
    // y = gelu(dw3x3(y))
    dw3x3_kernel<<<PP*64/256, 256, 0, stream>>>(Bb, OP1T, op1_b, Cb);
    // dense = conv1x1(y) + x  (into d_out; xh/a2h alias dead now)
    conv1x1_mfma<256,256,0,true,false,false><<<PP/64, 256, 0, stream>>>(Cb, WH_OP2, op2_b, A, D, nullptr);
    // attn = softmax-xattn(dense, t) + dense*alpha
    attn_kernel<<<BB*HH, 256, 0, stream>>>(D, TOK, alpha, Bb);
    // o = gelu(conv1x1_128(attn))
    conv1x1_mfma<256,128,1,false,false,false><<<PP/64, 256, 0, stream>>>(Bb, WH_OUT0, out0_b, nullptr, Cb, nullptr);
    // o = conv1x1(o) -> NHWC into A
    conv1x1_mfma<128,256,0,false,false,false><<<PP/64, 256, 0, stream>>>(Cb, WH_OUT1, out1_b, nullptr, A, nullptr);
    // NHWC -> NCHW final output
    nhwc_to_nchw_kernel<<<dim3(HWs/32, CC/32, BB), dim3(32,8), 0, stream>>>(A, (float*)d_out);
}